// Round 7
// baseline (265.266 us; speedup 1.0000x reference)
//
#include <hip/hip_runtime.h>
#include <hip/hip_fp16.h>
#include <math.h>

#define TPB 256
#define NPB 512          // nodes per bucket (power of 2)
#define NPB_SHIFT 9
#define EPB 8192         // edges per phase-A chunk (= one block's private segment)
#define EPW 16           // EPB / 512 threads
#define BCAP 12288       // per-bucket LDS capacity (mean ~8192, +45 sigma)

typedef float v2f __attribute__((ext_vector_type(2)));

__device__ __forceinline__ float leaky_relu(float v) { return v > 0.0f ? v : 0.01f * v; }

__device__ __forceinline__ float dot4(float4 a, float4 b) {
    return a.x * b.x + a.y * b.y + a.z * b.z + a.w * b.w;
}
__device__ __forceinline__ float4 f4_scale(float4 a, float s) {
    return make_float4(a.x * s, a.y * s, a.z * s, a.w * s);
}
// a*r + w*y
__device__ __forceinline__ float4 f4_rescale_acc(float4 a, float r, float w, float4 y) {
    return make_float4(fmaf(a.x, r, w * y.x), fmaf(a.y, r, w * y.y),
                       fmaf(a.z, r, w * y.z), fmaf(a.w, r, w * y.w));
}
__device__ __forceinline__ float4 shfl_xor4(float4 v, int d) {
    return make_float4(__shfl_xor(v.x, d, 64), __shfl_xor(v.y, d, 64),
                       __shfl_xor(v.z, d, 64), __shfl_xor(v.w, d, 64));
}
__device__ __forceinline__ float4 leaky4(float4 v) {
    return make_float4(leaky_relu(v.x), leaky_relu(v.y), leaky_relu(v.z), leaky_relu(v.w));
}

// HW fp8 e4m3 (OCP) pack/unpack: 4 elements <-> one dword
__device__ __forceinline__ float4 dec4(unsigned w) {
    v2f lo = __builtin_amdgcn_cvt_pk_f32_fp8((int)w, false);
    v2f hi = __builtin_amdgcn_cvt_pk_f32_fp8((int)w, true);
    return make_float4(lo.x, lo.y, hi.x, hi.y);
}
__device__ __forceinline__ unsigned enc4(float4 v) {
    int r = __builtin_amdgcn_cvt_pk_fp8_f32(v.x, v.y, 0, false);
    r = __builtin_amdgcn_cvt_pk_fp8_f32(v.z, v.w, r, true);
    return (unsigned)r;
}

// fp16 quarter helpers (MLP input rows)
__device__ __forceinline__ float4 load_h4(const __half* row, int l) {
    union { float2 f; __half h[4]; } u;
    u.f = ((const float2*)row)[l];
    return make_float4(__half2float(u.h[0]), __half2float(u.h[1]),
                       __half2float(u.h[2]), __half2float(u.h[3]));
}
__device__ __forceinline__ void store_h4(__half* row, int l, float4 v) {
    union { float2 f; __half h[4]; } u;
    u.h[0] = __float2half(v.x); u.h[1] = __float2half(v.y);
    u.h[2] = __float2half(v.z); u.h[3] = __float2half(v.w);
    ((float2*)row)[l] = u.f;
}

// ---------------- build phase A: per-chunk LDS counting sort ----------------
// Each block owns edges [c*EPB, (c+1)*EPB): histogram by bucket, scan, LDS
// scatter, then stream the sorted chunk to its PRIVATE contiguous segment of
// bdata (fully coalesced lines; zero global atomics — kills round-6's 3.1x
// write amplification + bcursor contention). Also writes per-(chunk,bucket)
// base/count tables (coalesced).
__global__ void k_binA(const int* __restrict__ src, const int* __restrict__ dst,
                       unsigned* __restrict__ bdata, int* __restrict__ cbase,
                       int* __restrict__ ccnt, int E, int K) {
    __shared__ int hist[512];
    __shared__ int scan_[512];
    __shared__ unsigned lcol[EPB];   // 32 KB
    int t = threadIdx.x;
    int c = blockIdx.x;
    int e0 = c * EPB;
    int e1 = min(e0 + EPB, E);
    hist[t] = 0;
    __syncthreads();
    int myd[EPW], mys[EPW];
#pragma unroll
    for (int k = 0; k < EPW; ++k) {
        int e = e0 + t + k * 512;
        int d = (e < e1) ? dst[e] : -1;
        mys[k] = (e < e1) ? src[e] : 0;
        myd[k] = d;
        if (d >= 0) atomicAdd(&hist[d >> NPB_SHIFT], 1);
    }
    __syncthreads();
    int v = hist[t];
    scan_[t] = v;
    __syncthreads();
    for (int off = 1; off < 512; off <<= 1) {
        int a = (t >= off) ? scan_[t - off] : 0;
        __syncthreads();
        scan_[t] += a;
        __syncthreads();
    }
    int excl = scan_[t] - v;
    if (t < K) {
        cbase[(size_t)c * K + t] = excl;
        ccnt[(size_t)c * K + t] = v;
    }
    __syncthreads();
    hist[t] = excl;   // reuse as cursor
    __syncthreads();
#pragma unroll
    for (int k = 0; k < EPW; ++k) {
        int d = myd[k];
        if (d >= 0) {
            int p = atomicAdd(&hist[d >> NPB_SHIFT], 1);
            lcol[p] = ((unsigned)(d & (NPB - 1)) << 18) | (unsigned)mys[k];
        }
    }
    __syncthreads();
    unsigned* outp = bdata + (size_t)c * EPB;
    int tot = e1 - e0;
    for (int i = t; i < tot; i += 512) outp[i] = lcol[i];
}

// per-bucket totals: btot[b] = sum_c ccnt[c][b]
__global__ void k_bsum(const int* __restrict__ ccnt, int* __restrict__ btot,
                       int NC, int K) {
    int b = blockIdx.x, t = threadIdx.x;   // 64 threads
    int s = 0;
    for (int c = t; c < NC; c += 64) s += ccnt[(size_t)c * K + b];
#pragma unroll
    for (int off = 32; off > 0; off >>= 1) s += __shfl_down(s, off);
    if (t == 0) btot[b] = s;
}

// exclusive scan of bucket totals -> global col base per bucket; offs[N]=E
__global__ void k_bscan(const int* __restrict__ btot, int* __restrict__ bbase,
                        int K, int* __restrict__ offs, int N) {
    __shared__ int sh[512];
    int t = threadIdx.x;
    int v = (t < K) ? btot[t] : 0;
    sh[t] = v;
    __syncthreads();
    for (int off = 1; off < 512; off <<= 1) {
        int a = (t >= off) ? sh[t - off] : 0;
        __syncthreads();
        sh[t] += a;
        __syncthreads();
    }
    if (t < K) bbase[t] = sh[t] - v;
    if (t == K - 1) offs[N] = sh[t];
}

// ---------------- build phase B: per-bucket CSR from chunk segments ----------------
// One block per bucket. Scan this bucket's per-chunk counts, binary-search-
// gather its entries from the chunk segments (runs of ~21 contiguous dwords,
// load-balanced), then local degree->scan->scatter in LDS, stream col out.
__global__ void k_binB(const unsigned* __restrict__ bdata, const int* __restrict__ cbase,
                       const int* __restrict__ ccnt, const int* __restrict__ bbase,
                       int* __restrict__ offs, int* __restrict__ col,
                       int N, int NC, int K) {
    __shared__ int cscan[512];   // inclusive scan of per-chunk counts
    __shared__ int cb[512];      // per-chunk run base
    __shared__ int ldeg[NPB];
    __shared__ int lscan[NPB];
    __shared__ unsigned lcol[BCAP];   // 48 KB
    int b = blockIdx.x, t = threadIdx.x;
    int n0 = b << NPB_SHIFT;
    int nn = min(NPB, N - n0);
    int v = (t < NC) ? ccnt[(size_t)t * K + b] : 0;
    cb[t] = (t < NC) ? cbase[(size_t)t * K + b] : 0;
    cscan[t] = v;
    __syncthreads();
    for (int off = 1; off < 512; off <<= 1) {
        int a = (t >= off) ? cscan[t - off] : 0;
        __syncthreads();
        cscan[t] += a;
        __syncthreads();
    }
    int total = min(cscan[511], BCAP);
    int gb = bbase[b];
    ldeg[t] = 0;
    __syncthreads();
    // pass 1: histogram of local dst
    for (int p = t; p < total; p += 512) {
        int lo = 0, hi = NC - 1;
        while (lo < hi) { int mid = (lo + hi) >> 1; if (cscan[mid] > p) hi = mid; else lo = mid + 1; }
        int within = p - (lo > 0 ? cscan[lo - 1] : 0);
        unsigned e = bdata[(size_t)lo * EPB + cb[lo] + within];
        atomicAdd(&ldeg[e >> 18], 1);
    }
    __syncthreads();
    int dv = ldeg[t];
    lscan[t] = dv;
    __syncthreads();
    for (int off = 1; off < NPB; off <<= 1) {
        int a = (t >= off) ? lscan[t - off] : 0;
        __syncthreads();
        lscan[t] += a;
        __syncthreads();
    }
    int excl = lscan[t] - dv;
    if (t < nn) offs[n0 + t] = gb + excl;
    __syncthreads();
    ldeg[t] = excl;   // cursor
    __syncthreads();
    // pass 2: gather again + scatter into local CSR order
    for (int p = t; p < total; p += 512) {
        int lo = 0, hi = NC - 1;
        while (lo < hi) { int mid = (lo + hi) >> 1; if (cscan[mid] > p) hi = mid; else lo = mid + 1; }
        int within = p - (lo > 0 ? cscan[lo - 1] : 0);
        unsigned e = bdata[(size_t)lo * EPB + cb[lo] + within];
        int s_ = atomicAdd(&ldeg[e >> 18], 1);
        lcol[s_] = e & 0x3FFFFu;
    }
    __syncthreads();
    for (int i = t; i < total; i += 512) col[gb + i] = (int)lcol[i];
}

// ---------------- prep: fp32 rows -> normalized fp8 rows + fp32 norm ----------------
__global__ void k_prep(const float* __restrict__ x, uint4* __restrict__ xq,
                       float* __restrict__ nrm, int n) {
    int i = blockIdx.x * blockDim.x + threadIdx.x;
    if (i >= n) return;
    const float4* xp = (const float4*)(x + (size_t)i * 16);
    float4 a = xp[0], b = xp[1], c = xp[2], d = xp[3];
    float ss = dot4(a, a) + dot4(b, b) + dot4(c, c) + dot4(d, d);
    float nn = fmaxf(sqrtf(ss), 1e-12f);
    float inv = 1.0f / nn;
    nrm[i] = nn;
    xq[i] = make_uint4(enc4(f4_scale(a, inv)), enc4(f4_scale(b, inv)),
                       enc4(f4_scale(c, inv)), enc4(f4_scale(d, inv)));
}

// ---------------- AGNN conv: 4 lanes per node, full row per lane ----------------
__global__ __launch_bounds__(256, 4)
void k_agnn(const uint4* __restrict__ xq, const float* __restrict__ nrm,
            const int* __restrict__ offs, const int* __restrict__ col,
            const float* __restrict__ beta_ptr, int beta_idx,
            void* __restrict__ out, float* __restrict__ nrm_out,
            int n, int fp8_out) {
    int t = threadIdx.x;
    int l = t & 3;
    int i = blockIdx.x * (TPB / 4) + (t >> 2);
    if (i >= n) return;
    float bet = beta_ptr[beta_idx];
    uint4 rowi = xq[i];
    float4 x0 = dec4(rowi.x), x1 = dec4(rowi.y), x2 = dec4(rowi.z), x3 = dec4(rowi.w);
    float ni = nrm[i];
    float4 q0 = f4_scale(x0, bet), q1 = f4_scale(x1, bet),
           q2 = f4_scale(x2, bet), q3 = f4_scale(x3, bet);
    float m, s;
    float4 a0, a1, a2, a3;
    if (l == 0) {
        m = dot4(x0, q0) + dot4(x1, q1) + dot4(x2, q2) + dot4(x3, q3);  // beta*||xn||^2
        s = 1.0f;
        a0 = f4_scale(x0, ni); a1 = f4_scale(x1, ni);
        a2 = f4_scale(x2, ni); a3 = f4_scale(x3, ni);
    } else {
        m = -3.4e38f; s = 0.0f;
        a0 = a1 = a2 = a3 = make_float4(0.f, 0.f, 0.f, 0.f);
    }
    int e1 = offs[i + 1];
    int e = offs[i] + l;
    uint4 row = make_uint4(0, 0, 0, 0);
    float nj = 0.0f;
    if (e < e1) { int j = col[e]; row = xq[j]; nj = nrm[j]; }
    while (e < e1) {
        int en = e + 4;
        uint4 rowN = make_uint4(0, 0, 0, 0);
        float njN = 0.0f;
        if (en < e1) { int jn = col[en]; rowN = xq[jn]; njN = nrm[jn]; }
        float4 y0 = dec4(row.x), y1 = dec4(row.y), y2 = dec4(row.z), y3 = dec4(row.w);
        float d = dot4(y0, q0) + dot4(y1, q1) + dot4(y2, q2) + dot4(y3, q3);
        float nm = fmaxf(m, d);
        float r = __expf(m - nm);
        float w = __expf(d - nm);
        s = fmaf(s, r, w);
        float wn = w * nj;
        a0 = f4_rescale_acc(a0, r, wn, y0);
        a1 = f4_rescale_acc(a1, r, wn, y1);
        a2 = f4_rescale_acc(a2, r, wn, y2);
        a3 = f4_rescale_acc(a3, r, wn, y3);
        m = nm;
        row = rowN; nj = njN; e = en;
    }
#pragma unroll
    for (int d_ = 1; d_ < 4; d_ <<= 1) {
        float mo = __shfl_xor(m, d_, 64);
        float so = __shfl_xor(s, d_, 64);
        float nm = fmaxf(m, mo);
        float r = __expf(m - nm);
        float w = __expf(mo - nm);
        s = fmaf(s, r, so * w);
        a0 = f4_rescale_acc(a0, r, w, shfl_xor4(a0, d_));
        a1 = f4_rescale_acc(a1, r, w, shfl_xor4(a1, d_));
        a2 = f4_rescale_acc(a2, r, w, shfl_xor4(a2, d_));
        a3 = f4_rescale_acc(a3, r, w, shfl_xor4(a3, d_));
        m = nm;
    }
    float inv = 1.0f / (s + 1e-16f);
    float4 o0 = leaky4(f4_scale(a0, inv));
    float4 o1 = leaky4(f4_scale(a1, inv));
    float4 o2 = leaky4(f4_scale(a2, inv));
    float4 o3 = leaky4(f4_scale(a3, inv));
    float4 oq = (l == 0) ? o0 : (l == 1) ? o1 : (l == 2) ? o2 : o3;
    if (fp8_out) {
        float ss = dot4(o0, o0) + dot4(o1, o1) + dot4(o2, o2) + dot4(o3, o3);
        float nn = fmaxf(sqrtf(ss), 1e-12f);
        ((unsigned*)out)[(size_t)i * 4 + l] = enc4(f4_scale(oq, 1.0f / nn));
        if (l == 0) nrm_out[i] = nn;
    } else {
        store_h4((__half*)out + (size_t)i * 16, l, oq);
    }
}

// ---------------- MLP head + fused per-block logsumexp partials ----------------
__global__ void k_mlp(const __half* __restrict__ x, const int* __restrict__ home,
                      const int* __restrict__ away,
                      const float* __restrict__ w0, const float* __restrict__ b0,
                      const float* __restrict__ w1, const float* __restrict__ b1,
                      const float* __restrict__ w2, const float* __restrict__ b2,
                      float* __restrict__ z, float* __restrict__ bmax,
                      float* __restrict__ bsum, int nb) {
    __shared__ float sw0[192], sw1[96], sw2[48], sb0[6], sb1[16], sb2[3];
    __shared__ float rmax[4][3];
    __shared__ float rsum[4][3];
    int t = threadIdx.x;
    if (t < 192) sw0[t] = w0[t];
    if (t < 96)  sw1[t] = w1[t];
    if (t < 48)  sw2[t] = w2[t];
    if (t < 6)   sb0[t] = b0[t];
    if (t < 16)  sb1[t] = b1[t];
    if (t < 3)   sb2[t] = b2[t];
    __syncthreads();
    int i = blockIdx.x * blockDim.x + t;
    bool act = i < nb;
    float z0 = -3.4e38f, z1 = -3.4e38f, z2 = -3.4e38f;
    if (act) {
        float h[32];
        const __half* hr = x + (size_t)home[i] * 16;
        const __half* ar = x + (size_t)away[i] * 16;
#pragma unroll
        for (int k = 0; k < 4; ++k) {
            float4 v = load_h4(hr, k);
            h[4 * k + 0] = v.x; h[4 * k + 1] = v.y; h[4 * k + 2] = v.z; h[4 * k + 3] = v.w;
            float4 u = load_h4(ar, k);
            h[16 + 4 * k + 0] = u.x; h[16 + 4 * k + 1] = u.y;
            h[16 + 4 * k + 2] = u.z; h[16 + 4 * k + 3] = u.w;
        }
        float t0[6];
#pragma unroll
        for (int o = 0; o < 6; ++o) {
            float acc = sb0[o];
#pragma unroll
            for (int k = 0; k < 32; ++k) acc = fmaf(h[k], sw0[k * 6 + o], acc);
            t0[o] = leaky_relu(acc);
        }
        float t1[16];
#pragma unroll
        for (int o = 0; o < 16; ++o) {
            float acc = sb1[o];
#pragma unroll
            for (int k = 0; k < 6; ++k) acc = fmaf(t0[k], sw1[k * 16 + o], acc);
            t1[o] = leaky_relu(acc);
        }
        float zz[3];
#pragma unroll
        for (int o = 0; o < 3; ++o) {
            float acc = sb2[o];
#pragma unroll
            for (int k = 0; k < 16; ++k) acc = fmaf(t1[k], sw2[k * 3 + o], acc);
            zz[o] = leaky_relu(acc);
            z[(size_t)i * 3 + o] = zz[o];
        }
        z0 = zz[0]; z1 = zz[1]; z2 = zz[2];
    }
    float w0_ = z0, w1_ = z1, w2_ = z2;
#pragma unroll
    for (int off = 32; off > 0; off >>= 1) {
        w0_ = fmaxf(w0_, __shfl_down(w0_, off));
        w1_ = fmaxf(w1_, __shfl_down(w1_, off));
        w2_ = fmaxf(w2_, __shfl_down(w2_, off));
    }
    int wid = t >> 6;
    if ((t & 63) == 0) { rmax[wid][0] = w0_; rmax[wid][1] = w1_; rmax[wid][2] = w2_; }
    __syncthreads();
    float M0 = fmaxf(fmaxf(rmax[0][0], rmax[1][0]), fmaxf(rmax[2][0], rmax[3][0]));
    float M1 = fmaxf(fmaxf(rmax[0][1], rmax[1][1]), fmaxf(rmax[2][1], rmax[3][1]));
    float M2 = fmaxf(fmaxf(rmax[0][2], rmax[1][2]), fmaxf(rmax[2][2], rmax[3][2]));
    float e0 = act ? __expf(z0 - M0) : 0.0f;
    float e1 = act ? __expf(z1 - M1) : 0.0f;
    float e2 = act ? __expf(z2 - M2) : 0.0f;
#pragma unroll
    for (int off = 32; off > 0; off >>= 1) {
        e0 += __shfl_down(e0, off);
        e1 += __shfl_down(e1, off);
        e2 += __shfl_down(e2, off);
    }
    if ((t & 63) == 0) { rsum[wid][0] = e0; rsum[wid][1] = e1; rsum[wid][2] = e2; }
    __syncthreads();
    if (t == 0) {
        float S0 = rsum[0][0] + rsum[1][0] + rsum[2][0] + rsum[3][0];
        float S1 = rsum[0][1] + rsum[1][1] + rsum[2][1] + rsum[3][1];
        float S2 = rsum[0][2] + rsum[1][2] + rsum[2][2] + rsum[3][2];
        bmax[blockIdx.x * 3 + 0] = M0; bmax[blockIdx.x * 3 + 1] = M1; bmax[blockIdx.x * 3 + 2] = M2;
        bsum[blockIdx.x * 3 + 0] = S0; bsum[blockIdx.x * 3 + 1] = S1; bsum[blockIdx.x * 3 + 2] = S2;
    }
}

// merge per-block (max, sumexp) partials -> global (max, sumexp) per column
__global__ void k_lse(const float* __restrict__ bmax, const float* __restrict__ bsum,
                      float* __restrict__ gM, float* __restrict__ gS, int nblk) {
    __shared__ float lm[4][3];
    __shared__ float ls[4][3];
    int t = threadIdx.x;
    float M0 = -3.4e38f, M1 = -3.4e38f, M2 = -3.4e38f;
    float S0 = 0.f, S1 = 0.f, S2 = 0.f;
    for (int b = t; b < nblk; b += 256) {
        float m0 = bmax[b * 3 + 0], s0 = bsum[b * 3 + 0];
        float n0 = fmaxf(M0, m0); S0 = S0 * __expf(M0 - n0) + s0 * __expf(m0 - n0); M0 = n0;
        float m1 = bmax[b * 3 + 1], s1 = bsum[b * 3 + 1];
        float n1 = fmaxf(M1, m1); S1 = S1 * __expf(M1 - n1) + s1 * __expf(m1 - n1); M1 = n1;
        float m2 = bmax[b * 3 + 2], s2 = bsum[b * 3 + 2];
        float n2 = fmaxf(M2, m2); S2 = S2 * __expf(M2 - n2) + s2 * __expf(m2 - n2); M2 = n2;
    }
#pragma unroll
    for (int off = 32; off > 0; off >>= 1) {
        float mo, so, nm;
        mo = __shfl_down(M0, off); so = __shfl_down(S0, off);
        nm = fmaxf(M0, mo); S0 = S0 * __expf(M0 - nm) + so * __expf(mo - nm); M0 = nm;
        mo = __shfl_down(M1, off); so = __shfl_down(S1, off);
        nm = fmaxf(M1, mo); S1 = S1 * __expf(M1 - nm) + so * __expf(mo - nm); M1 = nm;
        mo = __shfl_down(M2, off); so = __shfl_down(S2, off);
        nm = fmaxf(M2, mo); S2 = S2 * __expf(M2 - nm) + so * __expf(mo - nm); M2 = nm;
    }
    int wid = t >> 6;
    if ((t & 63) == 0) {
        lm[wid][0] = M0; lm[wid][1] = M1; lm[wid][2] = M2;
        ls[wid][0] = S0; ls[wid][1] = S1; ls[wid][2] = S2;
    }
    __syncthreads();
    if (t == 0) {
        for (int w = 1; w < 4; ++w) {
            float nm;
            nm = fmaxf(M0, lm[w][0]); S0 = S0 * __expf(M0 - nm) + ls[w][0] * __expf(lm[w][0] - nm); M0 = nm;
            nm = fmaxf(M1, lm[w][1]); S1 = S1 * __expf(M1 - nm) + ls[w][1] * __expf(lm[w][1] - nm); M1 = nm;
            nm = fmaxf(M2, lm[w][2]); S2 = S2 * __expf(M2 - nm) + ls[w][2] * __expf(lm[w][2] - nm); M2 = nm;
        }
        gM[0] = M0; gM[1] = M1; gM[2] = M2;
        gS[0] = S0; gS[1] = S1; gS[2] = S2;
    }
}

__global__ void k_final(const float* __restrict__ z, const float* __restrict__ gM,
                        const float* __restrict__ gS, float* __restrict__ out, int total) {
    int i = blockIdx.x * blockDim.x + threadIdx.x;
    if (i >= total) return;
    int c = i % 3;
    out[i] = z[i] - gM[c] - logf(gS[c]);
}

extern "C" void kernel_launch(void* const* d_in, const int* in_sizes, int n_in,
                              void* d_out, int out_size, void* d_ws, size_t ws_size,
                              hipStream_t stream) {
    const float* embed = (const float*)d_in[0];
    const float* beta  = (const float*)d_in[1];
    const float* w0 = (const float*)d_in[2];
    const float* b0 = (const float*)d_in[3];
    const float* w1 = (const float*)d_in[4];
    const float* b1 = (const float*)d_in[5];
    const float* w2 = (const float*)d_in[6];
    const float* b2 = (const float*)d_in[7];
    const int* eidx = (const int*)d_in[8];
    const int* home = (const int*)d_in[9];
    const int* away = (const int*)d_in[10];

    const int N = in_sizes[0] / 16;
    const int E = in_sizes[8] / 2;
    const int B = in_sizes[9];
    const int* esrc = eidx;
    const int* edst = eidx + E;
    const int K = (N + NPB - 1) >> NPB_SHIFT;       // 391 buckets
    const int NC = (E + EPB - 1) / EPB;             // 391 chunks (must be <=512)

    char* ws = (char*)d_ws;
    size_t off = 0;
    auto alloc = [&](size_t bytes) -> char* {
        off = (off + 255) & ~(size_t)255;
        char* p = ws + off;
        off += bytes;
        return p;
    };
    // union region: bdata (build) aliases {xq1, nrm1, zbuf} (all written after binB)
    size_t bdata_bytes = (size_t)NC * EPB * 4;   // 12.8 MB
    size_t alias_bytes = (((size_t)N * 20 + 511) & ~(size_t)255) + (size_t)B * 3 * 4;
    char* U = alloc(bdata_bytes > alias_bytes ? bdata_bytes : alias_bytes);
    unsigned* bdata = (unsigned*)U;
    uint4* xq1  = (uint4*)U;                                               // N*16B fp8
    float* nrm1 = (float*)(U + (((size_t)N * 16 + 255) & ~(size_t)255));   // N*4B
    float* zbuf = (float*)(U + (((size_t)N * 20 + 511) & ~(size_t)255));   // B*3*4B

    int* offs    = (int*)alloc((size_t)(N + 1) * 4);
    int* colw    = (int*)alloc((size_t)E * 4);
    int* cbase   = (int*)alloc((size_t)NC * K * 4);
    int* ccnt    = (int*)alloc((size_t)NC * K * 4);
    int* btot    = (int*)alloc((size_t)K * 4);
    int* bbase   = (int*)alloc((size_t)K * 4);
    uint4* xq0   = (uint4*)alloc((size_t)N * 16);
    float* nrm0  = (float*)alloc((size_t)N * 4);
    __half* xh2  = (__half*)alloc((size_t)N * 32);
    const int nblkB = (B + TPB - 1) / TPB;
    float* bmax  = (float*)alloc((size_t)nblkB * 3 * 4);
    float* bsum  = (float*)alloc((size_t)nblkB * 3 * 4);
    float* gM    = (float*)alloc(16);
    float* gS    = (float*)alloc(16);
    (void)ws_size; (void)n_in; (void)out_size;

    k_binA<<<NC, 512, 0, stream>>>(esrc, edst, bdata, cbase, ccnt, E, K);
    k_bsum<<<K, 64, 0, stream>>>(ccnt, btot, NC, K);
    k_bscan<<<1, 512, 0, stream>>>(btot, bbase, K, offs, N);
    k_binB<<<K, 512, 0, stream>>>(bdata, cbase, ccnt, bbase, offs, colw, N, NC, K);

    const int nblkN = (N + TPB - 1) / TPB;
    const int nblkN4 = (N + (TPB / 4) - 1) / (TPB / 4);
    k_prep<<<nblkN, TPB, 0, stream>>>(embed, xq0, nrm0, N);
    k_agnn<<<nblkN4, TPB, 0, stream>>>(xq0, nrm0, offs, colw, beta, 0, xq1, nrm1, N, 1);
    k_agnn<<<nblkN4, TPB, 0, stream>>>(xq1, nrm1, offs, colw, beta, 1, xh2, nullptr, N, 0);

    k_mlp<<<nblkB, TPB, 0, stream>>>(xh2, home, away, w0, b0, w1, b1, w2, b2,
                                     zbuf, bmax, bsum, B);
    k_lse<<<1, 256, 0, stream>>>(bmax, bsum, gM, gS, nblkB);
    const int total = B * 3;
    k_final<<<(total + TPB - 1) / TPB, TPB, 0, stream>>>(zbuf, gM, gS, (float*)d_out, total);
}

// Round 8
// 262.764 us; speedup vs baseline: 1.0095x; 1.0095x over previous
//
#include <hip/hip_runtime.h>
#include <hip/hip_fp16.h>
#include <math.h>

#define TPB 256
#define NPB 512          // nodes per bucket (power of 2)
#define NPB_SHIFT 9
#define EPB 8192         // edges per phase-A chunk (= one block's private segment)
#define EPW 16           // EPB / 512 threads
#define BCAP 12288       // per-bucket capacity (mean ~8192, +45 sigma)
#define STASH 24         // BCAP / 512

typedef float v2f __attribute__((ext_vector_type(2)));

__device__ __forceinline__ float leaky_relu(float v) { return v > 0.0f ? v : 0.01f * v; }

__device__ __forceinline__ float dot4(float4 a, float4 b) {
    return a.x * b.x + a.y * b.y + a.z * b.z + a.w * b.w;
}
__device__ __forceinline__ float4 f4_scale(float4 a, float s) {
    return make_float4(a.x * s, a.y * s, a.z * s, a.w * s);
}
// a*r + w*y
__device__ __forceinline__ float4 f4_rescale_acc(float4 a, float r, float w, float4 y) {
    return make_float4(fmaf(a.x, r, w * y.x), fmaf(a.y, r, w * y.y),
                       fmaf(a.z, r, w * y.z), fmaf(a.w, r, w * y.w));
}
__device__ __forceinline__ float4 shfl_xor4(float4 v, int d) {
    return make_float4(__shfl_xor(v.x, d, 64), __shfl_xor(v.y, d, 64),
                       __shfl_xor(v.z, d, 64), __shfl_xor(v.w, d, 64));
}
__device__ __forceinline__ float4 leaky4(float4 v) {
    return make_float4(leaky_relu(v.x), leaky_relu(v.y), leaky_relu(v.z), leaky_relu(v.w));
}

// HW fp8 e4m3 (OCP) pack/unpack: 4 elements <-> one dword
__device__ __forceinline__ float4 dec4(unsigned w) {
    v2f lo = __builtin_amdgcn_cvt_pk_f32_fp8((int)w, false);
    v2f hi = __builtin_amdgcn_cvt_pk_f32_fp8((int)w, true);
    return make_float4(lo.x, lo.y, hi.x, hi.y);
}
__device__ __forceinline__ unsigned enc4(float4 v) {
    int r = __builtin_amdgcn_cvt_pk_fp8_f32(v.x, v.y, 0, false);
    r = __builtin_amdgcn_cvt_pk_fp8_f32(v.z, v.w, r, true);
    return (unsigned)r;
}

// fp16 quarter helpers (MLP input rows)
__device__ __forceinline__ float4 load_h4(const __half* row, int l) {
    union { float2 f; __half h[4]; } u;
    u.f = ((const float2*)row)[l];
    return make_float4(__half2float(u.h[0]), __half2float(u.h[1]),
                       __half2float(u.h[2]), __half2float(u.h[3]));
}
__device__ __forceinline__ void store_h4(__half* row, int l, float4 v) {
    union { float2 f; __half h[4]; } u;
    u.h[0] = __float2half(v.x); u.h[1] = __float2half(v.y);
    u.h[2] = __float2half(v.z); u.h[3] = __float2half(v.w);
    ((float2*)row)[l] = u.f;
}

// ---------------- build phase A (+ fused prep) ----------------
// Per-chunk LDS counting sort -> private contiguous bdata segment (coalesced,
// zero global atomics). Tail: fp32 embed row -> normalized fp8 row + norm
// (grid NC*512 >= N), overlapping the LDS-heavy sort with prep's global work.
__global__ void k_binA(const int* __restrict__ src, const int* __restrict__ dst,
                       unsigned* __restrict__ bdata, int* __restrict__ cbase,
                       int* __restrict__ ccnt, int E, int K,
                       const float* __restrict__ x, uint4* __restrict__ xq,
                       float* __restrict__ nrm, int N) {
    __shared__ int hist[512];
    __shared__ int scan_[512];
    __shared__ unsigned lcol[EPB];   // 32 KB
    int t = threadIdx.x;
    int c = blockIdx.x;
    int e0 = c * EPB;
    int e1 = min(e0 + EPB, E);
    hist[t] = 0;
    __syncthreads();
    int myd[EPW], mys[EPW];
#pragma unroll
    for (int k = 0; k < EPW; ++k) {
        int e = e0 + t + k * 512;
        int d = (e < e1) ? dst[e] : -1;
        mys[k] = (e < e1) ? src[e] : 0;
        myd[k] = d;
        if (d >= 0) atomicAdd(&hist[d >> NPB_SHIFT], 1);
    }
    __syncthreads();
    int v = hist[t];
    scan_[t] = v;
    __syncthreads();
    for (int off = 1; off < 512; off <<= 1) {
        int a = (t >= off) ? scan_[t - off] : 0;
        __syncthreads();
        scan_[t] += a;
        __syncthreads();
    }
    int excl = scan_[t] - v;
    if (t < K) {
        cbase[(size_t)c * K + t] = excl;
        ccnt[(size_t)c * K + t] = v;
    }
    __syncthreads();
    hist[t] = excl;   // reuse as cursor
    __syncthreads();
#pragma unroll
    for (int k = 0; k < EPW; ++k) {
        int d = myd[k];
        if (d >= 0) {
            int p = atomicAdd(&hist[d >> NPB_SHIFT], 1);
            lcol[p] = ((unsigned)(d & (NPB - 1)) << 18) | (unsigned)mys[k];
        }
    }
    __syncthreads();
    unsigned* outp = bdata + (size_t)c * EPB;
    int tot = e1 - e0;
    for (int i = t; i < tot; i += 512) outp[i] = lcol[i];
    // ---- fused prep ----
    int i = c * 512 + t;
    if (i < N) {
        const float4* xp = (const float4*)(x + (size_t)i * 16);
        float4 a = xp[0], b = xp[1], cc = xp[2], d = xp[3];
        float ss = dot4(a, a) + dot4(b, b) + dot4(cc, cc) + dot4(d, d);
        float nn = fmaxf(sqrtf(ss), 1e-12f);
        float inv = 1.0f / nn;
        nrm[i] = nn;
        xq[i] = make_uint4(enc4(f4_scale(a, inv)), enc4(f4_scale(b, inv)),
                           enc4(f4_scale(cc, inv)), enc4(f4_scale(d, inv)));
    }
}

// per-bucket totals (coalesced column sums) + exclusive scan, one block
__global__ void k_bscan(const int* __restrict__ ccnt, int NC, int K,
                        int* __restrict__ bbase, int* __restrict__ offs, int N) {
    __shared__ int sh[512];
    int t = threadIdx.x;
    int s = 0;
    if (t < K) {
        int c = 0;
        for (; c + 4 <= NC; c += 4) {
            s += ccnt[(size_t)c * K + t] + ccnt[(size_t)(c + 1) * K + t] +
                 ccnt[(size_t)(c + 2) * K + t] + ccnt[(size_t)(c + 3) * K + t];
        }
        for (; c < NC; ++c) s += ccnt[(size_t)c * K + t];
    }
    sh[t] = s;
    __syncthreads();
    for (int off = 1; off < 512; off <<= 1) {
        int a = (t >= off) ? sh[t - off] : 0;
        __syncthreads();
        sh[t] += a;
        __syncthreads();
    }
    if (t < K) bbase[t] = sh[t] - s;
    if (t == K - 1) offs[N] = sh[t];
}

// ---------------- build phase B: per-bucket CSR, single global pass ----------------
// Gather each entry from the chunk segments ONCE (binary search over the
// chunk-count scan), stash in compile-time-indexed registers, histogram in the
// same pass; after the local scan, scatter from registers into LDS and stream
// col out coalesced. (v1 did the search+gather twice — this halves it.)
__global__ void k_binB(const unsigned* __restrict__ bdata, const int* __restrict__ cbase,
                       const int* __restrict__ ccnt, const int* __restrict__ bbase,
                       int* __restrict__ offs, int* __restrict__ col,
                       int N, int NC, int K) {
    __shared__ int cscan[512];   // inclusive scan of per-chunk counts
    __shared__ int cb[512];      // per-chunk run base
    __shared__ int ldeg[NPB];
    __shared__ int lscan[NPB];
    __shared__ unsigned lcol[BCAP];   // 48 KB
    int b = blockIdx.x, t = threadIdx.x;
    int n0 = b << NPB_SHIFT;
    int nn = min(NPB, N - n0);
    int v = (t < NC) ? ccnt[(size_t)t * K + b] : 0;
    cb[t] = (t < NC) ? cbase[(size_t)t * K + b] : 0;
    cscan[t] = v;
    __syncthreads();
    for (int off = 1; off < 512; off <<= 1) {
        int a = (t >= off) ? cscan[t - off] : 0;
        __syncthreads();
        cscan[t] += a;
        __syncthreads();
    }
    int total = min(cscan[511], BCAP);
    int gb = bbase[b];
    ldeg[t] = 0;
    __syncthreads();
    // single gather pass: global read + register stash + histogram
    unsigned st[STASH];
#pragma unroll
    for (int k = 0; k < STASH; ++k) {
        int p = t + k * 512;
        unsigned e = 0xFFFFFFFFu;
        if (p < total) {
            int lo = 0, hi = NC - 1;
            while (lo < hi) { int mid = (lo + hi) >> 1; if (cscan[mid] > p) hi = mid; else lo = mid + 1; }
            int within = p - (lo > 0 ? cscan[lo - 1] : 0);
            e = bdata[(size_t)lo * EPB + cb[lo] + within];
            atomicAdd(&ldeg[e >> 18], 1);
        }
        st[k] = e;
    }
    __syncthreads();
    int dv = ldeg[t];
    lscan[t] = dv;
    __syncthreads();
    for (int off = 1; off < NPB; off <<= 1) {
        int a = (t >= off) ? lscan[t - off] : 0;
        __syncthreads();
        lscan[t] += a;
        __syncthreads();
    }
    int excl = lscan[t] - dv;
    if (t < nn) offs[n0 + t] = gb + excl;
    __syncthreads();
    ldeg[t] = excl;   // cursor
    __syncthreads();
    // scatter from registers into local CSR order
#pragma unroll
    for (int k = 0; k < STASH; ++k) {
        unsigned e = st[k];
        if (e != 0xFFFFFFFFu) {
            int s_ = atomicAdd(&ldeg[e >> 18], 1);
            lcol[s_] = e & 0x3FFFFu;
        }
    }
    __syncthreads();
    for (int i = t; i < total; i += 512) col[gb + i] = (int)lcol[i];
}

// ---------------- AGNN conv: 4 lanes per node, full row per lane ----------------
// Depth-2 software pipeline: two edges' (row,nrm) in flight per lane.
__global__ void k_agnn(const uint4* __restrict__ xq, const float* __restrict__ nrm,
                       const int* __restrict__ offs, const int* __restrict__ col,
                       const float* __restrict__ beta_ptr, int beta_idx,
                       void* __restrict__ out, float* __restrict__ nrm_out,
                       int n, int fp8_out) {
    int t = threadIdx.x;
    int l = t & 3;
    int i = blockIdx.x * (TPB / 4) + (t >> 2);
    if (i >= n) return;
    float bet = beta_ptr[beta_idx];
    uint4 rowi = xq[i];
    float4 x0 = dec4(rowi.x), x1 = dec4(rowi.y), x2 = dec4(rowi.z), x3 = dec4(rowi.w);
    float ni = nrm[i];
    float4 q0 = f4_scale(x0, bet), q1 = f4_scale(x1, bet),
           q2 = f4_scale(x2, bet), q3 = f4_scale(x3, bet);
    float m, s;
    float4 a0, a1, a2, a3;
    if (l == 0) {
        m = dot4(x0, q0) + dot4(x1, q1) + dot4(x2, q2) + dot4(x3, q3);  // beta*||xn||^2
        s = 1.0f;
        a0 = f4_scale(x0, ni); a1 = f4_scale(x1, ni);
        a2 = f4_scale(x2, ni); a3 = f4_scale(x3, ni);
    } else {
        m = -3.4e38f; s = 0.0f;
        a0 = a1 = a2 = a3 = make_float4(0.f, 0.f, 0.f, 0.f);
    }
    int e1 = offs[i + 1];
    int e = offs[i] + l;
    uint4 rA = make_uint4(0, 0, 0, 0), rB = make_uint4(0, 0, 0, 0);
    float nA = 0.0f, nB = 0.0f;
    if (e < e1) { int j = col[e]; rA = xq[j]; nA = nrm[j]; }
    if (e + 4 < e1) { int j = col[e + 4]; rB = xq[j]; nB = nrm[j]; }
    for (; e < e1; e += 4) {
        uint4 rC = make_uint4(0, 0, 0, 0);
        float nC = 0.0f;
        if (e + 8 < e1) { int j = col[e + 8]; rC = xq[j]; nC = nrm[j]; }
        float4 y0 = dec4(rA.x), y1 = dec4(rA.y), y2 = dec4(rA.z), y3 = dec4(rA.w);
        float d = dot4(y0, q0) + dot4(y1, q1) + dot4(y2, q2) + dot4(y3, q3);
        float nm = fmaxf(m, d);
        float r = __expf(m - nm);
        float w = __expf(d - nm);
        s = fmaf(s, r, w);
        float wn = w * nA;
        a0 = f4_rescale_acc(a0, r, wn, y0);
        a1 = f4_rescale_acc(a1, r, wn, y1);
        a2 = f4_rescale_acc(a2, r, wn, y2);
        a3 = f4_rescale_acc(a3, r, wn, y3);
        m = nm;
        rA = rB; nA = nB; rB = rC; nB = nC;
    }
#pragma unroll
    for (int d_ = 1; d_ < 4; d_ <<= 1) {
        float mo = __shfl_xor(m, d_, 64);
        float so = __shfl_xor(s, d_, 64);
        float nm = fmaxf(m, mo);
        float r = __expf(m - nm);
        float w = __expf(mo - nm);
        s = fmaf(s, r, so * w);
        a0 = f4_rescale_acc(a0, r, w, shfl_xor4(a0, d_));
        a1 = f4_rescale_acc(a1, r, w, shfl_xor4(a1, d_));
        a2 = f4_rescale_acc(a2, r, w, shfl_xor4(a2, d_));
        a3 = f4_rescale_acc(a3, r, w, shfl_xor4(a3, d_));
        m = nm;
    }
    float inv = 1.0f / (s + 1e-16f);
    float4 o0 = leaky4(f4_scale(a0, inv));
    float4 o1 = leaky4(f4_scale(a1, inv));
    float4 o2 = leaky4(f4_scale(a2, inv));
    float4 o3 = leaky4(f4_scale(a3, inv));
    float4 oq = (l == 0) ? o0 : (l == 1) ? o1 : (l == 2) ? o2 : o3;
    if (fp8_out) {
        float ss = dot4(o0, o0) + dot4(o1, o1) + dot4(o2, o2) + dot4(o3, o3);
        float nn = fmaxf(sqrtf(ss), 1e-12f);
        ((unsigned*)out)[(size_t)i * 4 + l] = enc4(f4_scale(oq, 1.0f / nn));
        if (l == 0) nrm_out[i] = nn;
    } else {
        store_h4((__half*)out + (size_t)i * 16, l, oq);
    }
}

// ---------------- MLP head + fused per-block logsumexp partials ----------------
__global__ void k_mlp(const __half* __restrict__ x, const int* __restrict__ home,
                      const int* __restrict__ away,
                      const float* __restrict__ w0, const float* __restrict__ b0,
                      const float* __restrict__ w1, const float* __restrict__ b1,
                      const float* __restrict__ w2, const float* __restrict__ b2,
                      float* __restrict__ z, float* __restrict__ bmax,
                      float* __restrict__ bsum, int nb) {
    __shared__ float sw0[192], sw1[96], sw2[48], sb0[6], sb1[16], sb2[3];
    __shared__ float rmax[4][3];
    __shared__ float rsum[4][3];
    int t = threadIdx.x;
    if (t < 192) sw0[t] = w0[t];
    if (t < 96)  sw1[t] = w1[t];
    if (t < 48)  sw2[t] = w2[t];
    if (t < 6)   sb0[t] = b0[t];
    if (t < 16)  sb1[t] = b1[t];
    if (t < 3)   sb2[t] = b2[t];
    __syncthreads();
    int i = blockIdx.x * blockDim.x + t;
    bool act = i < nb;
    float z0 = -3.4e38f, z1 = -3.4e38f, z2 = -3.4e38f;
    if (act) {
        float h[32];
        const __half* hr = x + (size_t)home[i] * 16;
        const __half* ar = x + (size_t)away[i] * 16;
#pragma unroll
        for (int k = 0; k < 4; ++k) {
            float4 v = load_h4(hr, k);
            h[4 * k + 0] = v.x; h[4 * k + 1] = v.y; h[4 * k + 2] = v.z; h[4 * k + 3] = v.w;
            float4 u = load_h4(ar, k);
            h[16 + 4 * k + 0] = u.x; h[16 + 4 * k + 1] = u.y;
            h[16 + 4 * k + 2] = u.z; h[16 + 4 * k + 3] = u.w;
        }
        float t0[6];
#pragma unroll
        for (int o = 0; o < 6; ++o) {
            float acc = sb0[o];
#pragma unroll
            for (int k = 0; k < 32; ++k) acc = fmaf(h[k], sw0[k * 6 + o], acc);
            t0[o] = leaky_relu(acc);
        }
        float t1[16];
#pragma unroll
        for (int o = 0; o < 16; ++o) {
            float acc = sb1[o];
#pragma unroll
            for (int k = 0; k < 6; ++k) acc = fmaf(t0[k], sw1[k * 16 + o], acc);
            t1[o] = leaky_relu(acc);
        }
        float zz[3];
#pragma unroll
        for (int o = 0; o < 3; ++o) {
            float acc = sb2[o];
#pragma unroll
            for (int k = 0; k < 16; ++k) acc = fmaf(t1[k], sw2[k * 3 + o], acc);
            zz[o] = leaky_relu(acc);
            z[(size_t)i * 3 + o] = zz[o];
        }
        z0 = zz[0]; z1 = zz[1]; z2 = zz[2];
    }
    float w0_ = z0, w1_ = z1, w2_ = z2;
#pragma unroll
    for (int off = 32; off > 0; off >>= 1) {
        w0_ = fmaxf(w0_, __shfl_down(w0_, off));
        w1_ = fmaxf(w1_, __shfl_down(w1_, off));
        w2_ = fmaxf(w2_, __shfl_down(w2_, off));
    }
    int wid = t >> 6;
    if ((t & 63) == 0) { rmax[wid][0] = w0_; rmax[wid][1] = w1_; rmax[wid][2] = w2_; }
    __syncthreads();
    float M0 = fmaxf(fmaxf(rmax[0][0], rmax[1][0]), fmaxf(rmax[2][0], rmax[3][0]));
    float M1 = fmaxf(fmaxf(rmax[0][1], rmax[1][1]), fmaxf(rmax[2][1], rmax[3][1]));
    float M2 = fmaxf(fmaxf(rmax[0][2], rmax[1][2]), fmaxf(rmax[2][2], rmax[3][2]));
    float e0 = act ? __expf(z0 - M0) : 0.0f;
    float e1 = act ? __expf(z1 - M1) : 0.0f;
    float e2 = act ? __expf(z2 - M2) : 0.0f;
#pragma unroll
    for (int off = 32; off > 0; off >>= 1) {
        e0 += __shfl_down(e0, off);
        e1 += __shfl_down(e1, off);
        e2 += __shfl_down(e2, off);
    }
    if ((t & 63) == 0) { rsum[wid][0] = e0; rsum[wid][1] = e1; rsum[wid][2] = e2; }
    __syncthreads();
    if (t == 0) {
        float S0 = rsum[0][0] + rsum[1][0] + rsum[2][0] + rsum[3][0];
        float S1 = rsum[0][1] + rsum[1][1] + rsum[2][1] + rsum[3][1];
        float S2 = rsum[0][2] + rsum[1][2] + rsum[2][2] + rsum[3][2];
        bmax[blockIdx.x * 3 + 0] = M0; bmax[blockIdx.x * 3 + 1] = M1; bmax[blockIdx.x * 3 + 2] = M2;
        bsum[blockIdx.x * 3 + 0] = S0; bsum[blockIdx.x * 3 + 1] = S1; bsum[blockIdx.x * 3 + 2] = S2;
    }
}

// merge per-block (max, sumexp) partials -> global per-column
__global__ void k_lse(const float* __restrict__ bmax, const float* __restrict__ bsum,
                      float* __restrict__ gM, float* __restrict__ gS, int nblk) {
    __shared__ float lm[4][3];
    __shared__ float ls[4][3];
    int t = threadIdx.x;
    float M0 = -3.4e38f, M1 = -3.4e38f, M2 = -3.4e38f;
    float S0 = 0.f, S1 = 0.f, S2 = 0.f;
    for (int b = t; b < nblk; b += 256) {
        float m0 = bmax[b * 3 + 0], s0 = bsum[b * 3 + 0];
        float n0 = fmaxf(M0, m0); S0 = S0 * __expf(M0 - n0) + s0 * __expf(m0 - n0); M0 = n0;
        float m1 = bmax[b * 3 + 1], s1 = bsum[b * 3 + 1];
        float n1 = fmaxf(M1, m1); S1 = S1 * __expf(M1 - n1) + s1 * __expf(m1 - n1); M1 = n1;
        float m2 = bmax[b * 3 + 2], s2 = bsum[b * 3 + 2];
        float n2 = fmaxf(M2, m2); S2 = S2 * __expf(M2 - n2) + s2 * __expf(m2 - n2); M2 = n2;
    }
#pragma unroll
    for (int off = 32; off > 0; off >>= 1) {
        float mo, so, nm;
        mo = __shfl_down(M0, off); so = __shfl_down(S0, off);
        nm = fmaxf(M0, mo); S0 = S0 * __expf(M0 - nm) + so * __expf(mo - nm); M0 = nm;
        mo = __shfl_down(M1, off); so = __shfl_down(S1, off);
        nm = fmaxf(M1, mo); S1 = S1 * __expf(M1 - nm) + so * __expf(mo - nm); M1 = nm;
        mo = __shfl_down(M2, off); so = __shfl_down(S2, off);
        nm = fmaxf(M2, mo); S2 = S2 * __expf(M2 - nm) + so * __expf(mo - nm); M2 = nm;
    }
    int wid = t >> 6;
    if ((t & 63) == 0) {
        lm[wid][0] = M0; lm[wid][1] = M1; lm[wid][2] = M2;
        ls[wid][0] = S0; ls[wid][1] = S1; ls[wid][2] = S2;
    }
    __syncthreads();
    if (t == 0) {
        for (int w = 1; w < 4; ++w) {
            float nm;
            nm = fmaxf(M0, lm[w][0]); S0 = S0 * __expf(M0 - nm) + ls[w][0] * __expf(lm[w][0] - nm); M0 = nm;
            nm = fmaxf(M1, lm[w][1]); S1 = S1 * __expf(M1 - nm) + ls[w][1] * __expf(lm[w][1] - nm); M1 = nm;
            nm = fmaxf(M2, lm[w][2]); S2 = S2 * __expf(M2 - nm) + ls[w][2] * __expf(lm[w][2] - nm); M2 = nm;
        }
        gM[0] = M0; gM[1] = M1; gM[2] = M2;
        gS[0] = S0; gS[1] = S1; gS[2] = S2;
    }
}

__global__ void k_final(const float* __restrict__ z, const float* __restrict__ gM,
                        const float* __restrict__ gS, float* __restrict__ out, int total) {
    int i = blockIdx.x * blockDim.x + threadIdx.x;
    if (i >= total) return;
    int c = i % 3;
    out[i] = z[i] - gM[c] - logf(gS[c]);
}

extern "C" void kernel_launch(void* const* d_in, const int* in_sizes, int n_in,
                              void* d_out, int out_size, void* d_ws, size_t ws_size,
                              hipStream_t stream) {
    const float* embed = (const float*)d_in[0];
    const float* beta  = (const float*)d_in[1];
    const float* w0 = (const float*)d_in[2];
    const float* b0 = (const float*)d_in[3];
    const float* w1 = (const float*)d_in[4];
    const float* b1 = (const float*)d_in[5];
    const float* w2 = (const float*)d_in[6];
    const float* b2 = (const float*)d_in[7];
    const int* eidx = (const int*)d_in[8];
    const int* home = (const int*)d_in[9];
    const int* away = (const int*)d_in[10];

    const int N = in_sizes[0] / 16;
    const int E = in_sizes[8] / 2;
    const int B = in_sizes[9];
    const int* esrc = eidx;
    const int* edst = eidx + E;
    const int K = (N + NPB - 1) >> NPB_SHIFT;       // 391 buckets
    const int NC = (E + EPB - 1) / EPB;             // 391 chunks (<=512)

    char* ws = (char*)d_ws;
    size_t off = 0;
    auto alloc = [&](size_t bytes) -> char* {
        off = (off + 255) & ~(size_t)255;
        char* p = ws + off;
        off += bytes;
        return p;
    };
    // union region: bdata (build) aliases {xq1, nrm1, zbuf} (all written after binB)
    size_t bdata_bytes = (size_t)NC * EPB * 4;   // 12.8 MB
    size_t alias_bytes = (((size_t)N * 20 + 511) & ~(size_t)255) + (size_t)B * 3 * 4;
    char* U = alloc(bdata_bytes > alias_bytes ? bdata_bytes : alias_bytes);
    unsigned* bdata = (unsigned*)U;
    uint4* xq1  = (uint4*)U;                                               // N*16B fp8
    float* nrm1 = (float*)(U + (((size_t)N * 16 + 255) & ~(size_t)255));   // N*4B
    float* zbuf = (float*)(U + (((size_t)N * 20 + 511) & ~(size_t)255));   // B*3*4B

    int* offs    = (int*)alloc((size_t)(N + 1) * 4);
    int* colw    = (int*)alloc((size_t)E * 4);
    int* cbase   = (int*)alloc((size_t)NC * K * 4);
    int* ccnt    = (int*)alloc((size_t)NC * K * 4);
    int* bbase   = (int*)alloc((size_t)K * 4);
    uint4* xq0   = (uint4*)alloc((size_t)N * 16);
    float* nrm0  = (float*)alloc((size_t)N * 4);
    __half* xh2  = (__half*)alloc((size_t)N * 32);
    const int nblkB = (B + TPB - 1) / TPB;
    float* bmax  = (float*)alloc((size_t)nblkB * 3 * 4);
    float* bsum  = (float*)alloc((size_t)nblkB * 3 * 4);
    float* gM    = (float*)alloc(16);
    float* gS    = (float*)alloc(16);
    (void)ws_size; (void)n_in; (void)out_size;

    k_binA<<<NC, 512, 0, stream>>>(esrc, edst, bdata, cbase, ccnt, E, K,
                                   embed, xq0, nrm0, N);
    k_bscan<<<1, 512, 0, stream>>>(ccnt, NC, K, bbase, offs, N);
    k_binB<<<K, 512, 0, stream>>>(bdata, cbase, ccnt, bbase, offs, colw, N, NC, K);

    const int nblkN4 = (N + (TPB / 4) - 1) / (TPB / 4);
    k_agnn<<<nblkN4, TPB, 0, stream>>>(xq0, nrm0, offs, colw, beta, 0, xq1, nrm1, N, 1);
    k_agnn<<<nblkN4, TPB, 0, stream>>>(xq1, nrm1, offs, colw, beta, 1, xh2, nullptr, N, 0);

    k_mlp<<<nblkB, TPB, 0, stream>>>(xh2, home, away, w0, b0, w1, b1, w2, b2,
                                     zbuf, bmax, bsum, B);
    k_lse<<<1, 256, 0, stream>>>(bmax, bsum, gM, gS, nblkB);
    const int total = B * 3;
    k_final<<<(total + TPB - 1) / TPB, TPB, 0, stream>>>(zbuf, gM, gS, (float*)d_out, total);
}

// Round 9
// 249.070 us; speedup vs baseline: 1.0650x; 1.0550x over previous
//
#include <hip/hip_runtime.h>
#include <hip/hip_fp16.h>
#include <math.h>

#define TPB 256
#define NPB 512          // nodes per bucket (power of 2)
#define NPB_SHIFT 9
#define EPB 8192         // edges per phase-A chunk (= one block's private segment)
#define EPW 16           // EPB / 512 threads
#define BCAP 12288       // per-bucket col-window capacity (mean ~8192, +45 sigma)

typedef float v2f __attribute__((ext_vector_type(2)));

__device__ __forceinline__ float leaky_relu(float v) { return v > 0.0f ? v : 0.01f * v; }

__device__ __forceinline__ float dot4(float4 a, float4 b) {
    return a.x * b.x + a.y * b.y + a.z * b.z + a.w * b.w;
}
__device__ __forceinline__ float4 f4_scale(float4 a, float s) {
    return make_float4(a.x * s, a.y * s, a.z * s, a.w * s);
}
// a += w*y
__device__ __forceinline__ float4 f4_acc(float4 a, float w, float4 y) {
    return make_float4(fmaf(w, y.x, a.x), fmaf(w, y.y, a.y),
                       fmaf(w, y.z, a.z), fmaf(w, y.w, a.w));
}
__device__ __forceinline__ float4 f4_add_shfl(float4 v, int d) {
    return make_float4(v.x + __shfl_xor(v.x, d, 64), v.y + __shfl_xor(v.y, d, 64),
                       v.z + __shfl_xor(v.z, d, 64), v.w + __shfl_xor(v.w, d, 64));
}
__device__ __forceinline__ float4 leaky4(float4 v) {
    return make_float4(leaky_relu(v.x), leaky_relu(v.y), leaky_relu(v.z), leaky_relu(v.w));
}

// HW fp8 e4m3 (OCP) pack/unpack: 4 elements <-> one dword
__device__ __forceinline__ float4 dec4(unsigned w) {
    v2f lo = __builtin_amdgcn_cvt_pk_f32_fp8((int)w, false);
    v2f hi = __builtin_amdgcn_cvt_pk_f32_fp8((int)w, true);
    return make_float4(lo.x, lo.y, hi.x, hi.y);
}
__device__ __forceinline__ unsigned enc4(float4 v) {
    int r = __builtin_amdgcn_cvt_pk_fp8_f32(v.x, v.y, 0, false);
    r = __builtin_amdgcn_cvt_pk_fp8_f32(v.z, v.w, r, true);
    return (unsigned)r;
}

// fp16 quarter helpers (MLP input rows)
__device__ __forceinline__ float4 load_h4(const __half* row, int l) {
    union { float2 f; __half h[4]; } u;
    u.f = ((const float2*)row)[l];
    return make_float4(__half2float(u.h[0]), __half2float(u.h[1]),
                       __half2float(u.h[2]), __half2float(u.h[3]));
}
__device__ __forceinline__ void store_h4(__half* row, int l, float4 v) {
    union { float2 f; __half h[4]; } u;
    u.h[0] = __float2half(v.x); u.h[1] = __float2half(v.y);
    u.h[2] = __float2half(v.z); u.h[3] = __float2half(v.w);
    ((float2*)row)[l] = u.f;
}

// ---------------- build phase A (+ fused prep) ----------------
// Per-chunk LDS counting sort -> private contiguous bdata segment (coalesced,
// zero global atomics). Tail: fp32 embed row -> normalized fp8 row + norm.
__global__ void k_binA(const int* __restrict__ src, const int* __restrict__ dst,
                       unsigned* __restrict__ bdata, int* __restrict__ cbase,
                       int* __restrict__ ccnt, int E, int K,
                       const float* __restrict__ x, uint4* __restrict__ xq,
                       float* __restrict__ nrm, int N) {
    __shared__ int hist[512];
    __shared__ int scan_[512];
    __shared__ unsigned lcol[EPB];   // 32 KB
    int t = threadIdx.x;
    int c = blockIdx.x;
    int e0 = c * EPB;
    int e1 = min(e0 + EPB, E);
    hist[t] = 0;
    __syncthreads();
    int myd[EPW], mys[EPW];
#pragma unroll
    for (int k = 0; k < EPW; ++k) {
        int e = e0 + t + k * 512;
        int d = (e < e1) ? dst[e] : -1;
        mys[k] = (e < e1) ? src[e] : 0;
        myd[k] = d;
        if (d >= 0) atomicAdd(&hist[d >> NPB_SHIFT], 1);
    }
    __syncthreads();
    int v = hist[t];
    scan_[t] = v;
    __syncthreads();
    for (int off = 1; off < 512; off <<= 1) {
        int a = (t >= off) ? scan_[t - off] : 0;
        __syncthreads();
        scan_[t] += a;
        __syncthreads();
    }
    int excl = scan_[t] - v;
    if (t < K) {
        cbase[(size_t)c * K + t] = excl;
        ccnt[(size_t)c * K + t] = v;
    }
    __syncthreads();
    hist[t] = excl;   // reuse as cursor
    __syncthreads();
#pragma unroll
    for (int k = 0; k < EPW; ++k) {
        int d = myd[k];
        if (d >= 0) {
            int p = atomicAdd(&hist[d >> NPB_SHIFT], 1);
            lcol[p] = ((unsigned)(d & (NPB - 1)) << 18) | (unsigned)mys[k];
        }
    }
    __syncthreads();
    unsigned* outp = bdata + (size_t)c * EPB;
    int tot = e1 - e0;
    for (int i = t; i < tot; i += 512) outp[i] = lcol[i];
    // ---- fused prep ----
    int i = c * 512 + t;
    if (i < N) {
        const float4* xp = (const float4*)(x + (size_t)i * 16);
        float4 a = xp[0], b = xp[1], cc = xp[2], d = xp[3];
        float ss = dot4(a, a) + dot4(b, b) + dot4(cc, cc) + dot4(d, d);
        float nn = fmaxf(sqrtf(ss), 1e-12f);
        float inv = 1.0f / nn;
        nrm[i] = nn;
        xq[i] = make_uint4(enc4(f4_scale(a, inv)), enc4(f4_scale(b, inv)),
                           enc4(f4_scale(cc, inv)), enc4(f4_scale(d, inv)));
    }
}

// ---------------- build phase B: per-bucket CSR, thread-per-run ----------------
// One block per bucket; thread c walks chunk c's contiguous run for this
// bucket (no binary search, no LDS col staging). Pass 1: LDS degree
// histogram. Scan -> per-node start/end (col window is the bucket's private
// padded slot b*BCAP — no global bucket scan needed at all). Pass 2: cursor-
// scatter col directly to global (4B scatters confined to a 48KB L2-resident
// window -> write-combines).
__global__ void k_binB(const unsigned* __restrict__ bdata, const int* __restrict__ cbase,
                       const int* __restrict__ ccnt,
                       int* __restrict__ startp, int* __restrict__ endp,
                       int* __restrict__ col, int N, int NC, int K) {
    __shared__ int cb[512];
    __shared__ int cc[512];
    __shared__ int ldeg[NPB];
    __shared__ int lscan[NPB];
    int b = blockIdx.x, t = threadIdx.x;
    int n0 = b << NPB_SHIFT;
    int nn = min(NPB, N - n0);
    cb[t] = (t < NC) ? cbase[(size_t)t * K + b] : 0;
    cc[t] = (t < NC) ? ccnt[(size_t)t * K + b] : 0;
    ldeg[t] = 0;
    __syncthreads();
    int mycnt = (t < NC) ? cc[t] : 0;
    const unsigned* myp = bdata + (size_t)t * EPB + cb[t];
    for (int k = 0; k < mycnt; ++k) {
        unsigned e = myp[k];
        atomicAdd(&ldeg[e >> 18], 1);
    }
    __syncthreads();
    int dv = ldeg[t];
    lscan[t] = dv;
    __syncthreads();
    for (int off = 1; off < NPB; off <<= 1) {
        int a = (t >= off) ? lscan[t - off] : 0;
        __syncthreads();
        lscan[t] += a;
        __syncthreads();
    }
    int excl = lscan[t] - dv;
    int gb = b * BCAP;
    if (t < nn) {
        startp[n0 + t] = gb + excl;
        endp[n0 + t] = gb + excl + dv;
    }
    __syncthreads();
    ldeg[t] = excl;   // cursor
    __syncthreads();
    for (int k = 0; k < mycnt; ++k) {
        unsigned e = myp[k];
        int pos = atomicAdd(&ldeg[e >> 18], 1);
        col[gb + pos] = (int)(e & 0x3FFFFu);
    }
}

// ---------------- AGNN conv: 4 lanes per node, full row per lane ----------------
// No online-softmax: |alpha| <= |beta|*(1+eps) so exp can't overflow; compute
// s = sum exp(alpha), acc = sum exp(alpha)*x directly. Loop body is pure
// independent FMAs (no fmax->exp->rescale serial chain). Depth-2 prefetch.
__global__ void k_agnn(const uint4* __restrict__ xq, const float* __restrict__ nrm,
                       const int* __restrict__ startp, const int* __restrict__ endp,
                       const int* __restrict__ col,
                       const float* __restrict__ beta_ptr, int beta_idx,
                       void* __restrict__ out, float* __restrict__ nrm_out,
                       int n, int fp8_out) {
    int t = threadIdx.x;
    int l = t & 3;
    int i = blockIdx.x * (TPB / 4) + (t >> 2);
    if (i >= n) return;
    float bet = beta_ptr[beta_idx];
    uint4 rowi = xq[i];
    float4 x0 = dec4(rowi.x), x1 = dec4(rowi.y), x2 = dec4(rowi.z), x3 = dec4(rowi.w);
    float ni = nrm[i];
    float4 q0 = f4_scale(x0, bet), q1 = f4_scale(x1, bet),
           q2 = f4_scale(x2, bet), q3 = f4_scale(x3, bet);
    float s;
    float4 a0, a1, a2, a3;
    if (l == 0) {
        float aself = dot4(x0, q0) + dot4(x1, q1) + dot4(x2, q2) + dot4(x3, q3);
        float w = __expf(aself);
        s = w;
        float wi = w * ni;   // exp(a_self) * ||x_i|| (x_i = xn_i * ||x_i||)
        a0 = f4_scale(x0, wi); a1 = f4_scale(x1, wi);
        a2 = f4_scale(x2, wi); a3 = f4_scale(x3, wi);
    } else {
        s = 0.0f;
        a0 = a1 = a2 = a3 = make_float4(0.f, 0.f, 0.f, 0.f);
    }
    int e1 = endp[i];
    int e = startp[i] + l;
    uint4 rA = make_uint4(0, 0, 0, 0), rB = make_uint4(0, 0, 0, 0);
    float nA = 0.0f, nB = 0.0f;
    if (e < e1) { int j = col[e]; rA = xq[j]; nA = nrm[j]; }
    if (e + 4 < e1) { int j = col[e + 4]; rB = xq[j]; nB = nrm[j]; }
    for (; e < e1; e += 4) {
        uint4 rC = make_uint4(0, 0, 0, 0);
        float nC = 0.0f;
        if (e + 8 < e1) { int j = col[e + 8]; rC = xq[j]; nC = nrm[j]; }
        float4 y0 = dec4(rA.x), y1 = dec4(rA.y), y2 = dec4(rA.z), y3 = dec4(rA.w);
        float d = dot4(y0, q0) + dot4(y1, q1) + dot4(y2, q2) + dot4(y3, q3);
        float w = __expf(d);
        s += w;
        float wn = w * nA;
        a0 = f4_acc(a0, wn, y0);
        a1 = f4_acc(a1, wn, y1);
        a2 = f4_acc(a2, wn, y2);
        a3 = f4_acc(a3, wn, y3);
        rA = rB; nA = nB; rB = rC; nB = nC;
    }
    // merge 4 lane-states: plain sums (butterfly)
#pragma unroll
    for (int d_ = 1; d_ < 4; d_ <<= 1) {
        s += __shfl_xor(s, d_, 64);
        a0 = f4_add_shfl(a0, d_);
        a1 = f4_add_shfl(a1, d_);
        a2 = f4_add_shfl(a2, d_);
        a3 = f4_add_shfl(a3, d_);
    }
    float inv = 1.0f / (s + 1e-16f);
    float4 o0 = leaky4(f4_scale(a0, inv));
    float4 o1 = leaky4(f4_scale(a1, inv));
    float4 o2 = leaky4(f4_scale(a2, inv));
    float4 o3 = leaky4(f4_scale(a3, inv));
    float4 oq = (l == 0) ? o0 : (l == 1) ? o1 : (l == 2) ? o2 : o3;
    if (fp8_out) {
        float ss = dot4(o0, o0) + dot4(o1, o1) + dot4(o2, o2) + dot4(o3, o3);
        float nn = fmaxf(sqrtf(ss), 1e-12f);
        ((unsigned*)out)[(size_t)i * 4 + l] = enc4(f4_scale(oq, 1.0f / nn));
        if (l == 0) nrm_out[i] = nn;
    } else {
        store_h4((__half*)out + (size_t)i * 16, l, oq);
    }
}

// ---------------- MLP head + fused per-block logsumexp partials ----------------
__global__ void k_mlp(const __half* __restrict__ x, const int* __restrict__ home,
                      const int* __restrict__ away,
                      const float* __restrict__ w0, const float* __restrict__ b0,
                      const float* __restrict__ w1, const float* __restrict__ b1,
                      const float* __restrict__ w2, const float* __restrict__ b2,
                      float* __restrict__ z, float* __restrict__ bmax,
                      float* __restrict__ bsum, int nb) {
    __shared__ float sw0[192], sw1[96], sw2[48], sb0[6], sb1[16], sb2[3];
    __shared__ float rmax[4][3];
    __shared__ float rsum[4][3];
    int t = threadIdx.x;
    if (t < 192) sw0[t] = w0[t];
    if (t < 96)  sw1[t] = w1[t];
    if (t < 48)  sw2[t] = w2[t];
    if (t < 6)   sb0[t] = b0[t];
    if (t < 16)  sb1[t] = b1[t];
    if (t < 3)   sb2[t] = b2[t];
    __syncthreads();
    int i = blockIdx.x * blockDim.x + t;
    bool act = i < nb;
    float z0 = -3.4e38f, z1 = -3.4e38f, z2 = -3.4e38f;
    if (act) {
        float h[32];
        const __half* hr = x + (size_t)home[i] * 16;
        const __half* ar = x + (size_t)away[i] * 16;
#pragma unroll
        for (int k = 0; k < 4; ++k) {
            float4 v = load_h4(hr, k);
            h[4 * k + 0] = v.x; h[4 * k + 1] = v.y; h[4 * k + 2] = v.z; h[4 * k + 3] = v.w;
            float4 u = load_h4(ar, k);
            h[16 + 4 * k + 0] = u.x; h[16 + 4 * k + 1] = u.y;
            h[16 + 4 * k + 2] = u.z; h[16 + 4 * k + 3] = u.w;
        }
        float t0[6];
#pragma unroll
        for (int o = 0; o < 6; ++o) {
            float acc = sb0[o];
#pragma unroll
            for (int k = 0; k < 32; ++k) acc = fmaf(h[k], sw0[k * 6 + o], acc);
            t0[o] = leaky_relu(acc);
        }
        float t1[16];
#pragma unroll
        for (int o = 0; o < 16; ++o) {
            float acc = sb1[o];
#pragma unroll
            for (int k = 0; k < 6; ++k) acc = fmaf(t0[k], sw1[k * 16 + o], acc);
            t1[o] = leaky_relu(acc);
        }
        float zz[3];
#pragma unroll
        for (int o = 0; o < 3; ++o) {
            float acc = sb2[o];
#pragma unroll
            for (int k = 0; k < 16; ++k) acc = fmaf(t1[k], sw2[k * 3 + o], acc);
            zz[o] = leaky_relu(acc);
            z[(size_t)i * 3 + o] = zz[o];
        }
        z0 = zz[0]; z1 = zz[1]; z2 = zz[2];
    }
    float w0_ = z0, w1_ = z1, w2_ = z2;
#pragma unroll
    for (int off = 32; off > 0; off >>= 1) {
        w0_ = fmaxf(w0_, __shfl_down(w0_, off));
        w1_ = fmaxf(w1_, __shfl_down(w1_, off));
        w2_ = fmaxf(w2_, __shfl_down(w2_, off));
    }
    int wid = t >> 6;
    if ((t & 63) == 0) { rmax[wid][0] = w0_; rmax[wid][1] = w1_; rmax[wid][2] = w2_; }
    __syncthreads();
    float M0 = fmaxf(fmaxf(rmax[0][0], rmax[1][0]), fmaxf(rmax[2][0], rmax[3][0]));
    float M1 = fmaxf(fmaxf(rmax[0][1], rmax[1][1]), fmaxf(rmax[2][1], rmax[3][1]));
    float M2 = fmaxf(fmaxf(rmax[0][2], rmax[1][2]), fmaxf(rmax[2][2], rmax[3][2]));
    float e0 = act ? __expf(z0 - M0) : 0.0f;
    float e1 = act ? __expf(z1 - M1) : 0.0f;
    float e2 = act ? __expf(z2 - M2) : 0.0f;
#pragma unroll
    for (int off = 32; off > 0; off >>= 1) {
        e0 += __shfl_down(e0, off);
        e1 += __shfl_down(e1, off);
        e2 += __shfl_down(e2, off);
    }
    if ((t & 63) == 0) { rsum[wid][0] = e0; rsum[wid][1] = e1; rsum[wid][2] = e2; }
    __syncthreads();
    if (t == 0) {
        float S0 = rsum[0][0] + rsum[1][0] + rsum[2][0] + rsum[3][0];
        float S1 = rsum[0][1] + rsum[1][1] + rsum[2][1] + rsum[3][1];
        float S2 = rsum[0][2] + rsum[1][2] + rsum[2][2] + rsum[3][2];
        bmax[blockIdx.x * 3 + 0] = M0; bmax[blockIdx.x * 3 + 1] = M1; bmax[blockIdx.x * 3 + 2] = M2;
        bsum[blockIdx.x * 3 + 0] = S0; bsum[blockIdx.x * 3 + 1] = S1; bsum[blockIdx.x * 3 + 2] = S2;
    }
}

// merge per-block (max, sumexp) partials -> global per-column
__global__ void k_lse(const float* __restrict__ bmax, const float* __restrict__ bsum,
                      float* __restrict__ gM, float* __restrict__ gS, int nblk) {
    __shared__ float lm[4][3];
    __shared__ float ls[4][3];
    int t = threadIdx.x;
    float M0 = -3.4e38f, M1 = -3.4e38f, M2 = -3.4e38f;
    float S0 = 0.f, S1 = 0.f, S2 = 0.f;
    for (int b = t; b < nblk; b += 256) {
        float m0 = bmax[b * 3 + 0], s0 = bsum[b * 3 + 0];
        float n0 = fmaxf(M0, m0); S0 = S0 * __expf(M0 - n0) + s0 * __expf(m0 - n0); M0 = n0;
        float m1 = bmax[b * 3 + 1], s1 = bsum[b * 3 + 1];
        float n1 = fmaxf(M1, m1); S1 = S1 * __expf(M1 - n1) + s1 * __expf(m1 - n1); M1 = n1;
        float m2 = bmax[b * 3 + 2], s2 = bsum[b * 3 + 2];
        float n2 = fmaxf(M2, m2); S2 = S2 * __expf(M2 - n2) + s2 * __expf(m2 - n2); M2 = n2;
    }
#pragma unroll
    for (int off = 32; off > 0; off >>= 1) {
        float mo, so, nm;
        mo = __shfl_down(M0, off); so = __shfl_down(S0, off);
        nm = fmaxf(M0, mo); S0 = S0 * __expf(M0 - nm) + so * __expf(mo - nm); M0 = nm;
        mo = __shfl_down(M1, off); so = __shfl_down(S1, off);
        nm = fmaxf(M1, mo); S1 = S1 * __expf(M1 - nm) + so * __expf(mo - nm); M1 = nm;
        mo = __shfl_down(M2, off); so = __shfl_down(S2, off);
        nm = fmaxf(M2, mo); S2 = S2 * __expf(M2 - nm) + so * __expf(mo - nm); M2 = nm;
    }
    int wid = t >> 6;
    if ((t & 63) == 0) {
        lm[wid][0] = M0; lm[wid][1] = M1; lm[wid][2] = M2;
        ls[wid][0] = S0; ls[wid][1] = S1; ls[wid][2] = S2;
    }
    __syncthreads();
    if (t == 0) {
        for (int w = 1; w < 4; ++w) {
            float nm;
            nm = fmaxf(M0, lm[w][0]); S0 = S0 * __expf(M0 - nm) + ls[w][0] * __expf(lm[w][0] - nm); M0 = nm;
            nm = fmaxf(M1, lm[w][1]); S1 = S1 * __expf(M1 - nm) + ls[w][1] * __expf(lm[w][1] - nm); M1 = nm;
            nm = fmaxf(M2, lm[w][2]); S2 = S2 * __expf(M2 - nm) + ls[w][2] * __expf(lm[w][2] - nm); M2 = nm;
        }
        gM[0] = M0; gM[1] = M1; gM[2] = M2;
        gS[0] = S0; gS[1] = S1; gS[2] = S2;
    }
}

__global__ void k_final(const float* __restrict__ z, const float* __restrict__ gM,
                        const float* __restrict__ gS, float* __restrict__ out, int total) {
    int i = blockIdx.x * blockDim.x + threadIdx.x;
    if (i >= total) return;
    int c = i % 3;
    out[i] = z[i] - gM[c] - logf(gS[c]);
}

extern "C" void kernel_launch(void* const* d_in, const int* in_sizes, int n_in,
                              void* d_out, int out_size, void* d_ws, size_t ws_size,
                              hipStream_t stream) {
    const float* embed = (const float*)d_in[0];
    const float* beta  = (const float*)d_in[1];
    const float* w0 = (const float*)d_in[2];
    const float* b0 = (const float*)d_in[3];
    const float* w1 = (const float*)d_in[4];
    const float* b1 = (const float*)d_in[5];
    const float* w2 = (const float*)d_in[6];
    const float* b2 = (const float*)d_in[7];
    const int* eidx = (const int*)d_in[8];
    const int* home = (const int*)d_in[9];
    const int* away = (const int*)d_in[10];

    const int N = in_sizes[0] / 16;
    const int E = in_sizes[8] / 2;
    const int B = in_sizes[9];
    const int* esrc = eidx;
    const int* edst = eidx + E;
    const int K = (N + NPB - 1) >> NPB_SHIFT;       // 391 buckets
    const int NC = (E + EPB - 1) / EPB;             // 391 chunks (<=512)

    char* ws = (char*)d_ws;
    size_t off = 0;
    auto alloc = [&](size_t bytes) -> char* {
        off = (off + 255) & ~(size_t)255;
        char* p = ws + off;
        off += bytes;
        return p;
    };
    // union region: bdata (build) aliases {xq1, nrm1, zbuf} (all written after binB)
    size_t bdata_bytes = (size_t)NC * EPB * 4;   // 12.8 MB
    size_t alias_bytes = (((size_t)N * 20 + 511) & ~(size_t)255) + (size_t)B * 3 * 4;
    char* U = alloc(bdata_bytes > alias_bytes ? bdata_bytes : alias_bytes);
    unsigned* bdata = (unsigned*)U;
    uint4* xq1  = (uint4*)U;                                               // N*16B fp8
    float* nrm1 = (float*)(U + (((size_t)N * 16 + 255) & ~(size_t)255));   // N*4B
    float* zbuf = (float*)(U + (((size_t)N * 20 + 511) & ~(size_t)255));   // B*3*4B

    int* startp  = (int*)alloc((size_t)N * 4);
    int* endp    = (int*)alloc((size_t)N * 4);
    int* colw    = (int*)alloc((size_t)K * BCAP * 4);   // padded per-bucket windows, 19.2 MB
    int* cbase   = (int*)alloc((size_t)NC * K * 4);
    int* ccnt    = (int*)alloc((size_t)NC * K * 4);
    uint4* xq0   = (uint4*)alloc((size_t)N * 16);
    float* nrm0  = (float*)alloc((size_t)N * 4);
    __half* xh2  = (__half*)alloc((size_t)N * 32);
    const int nblkB = (B + TPB - 1) / TPB;
    float* bmax  = (float*)alloc((size_t)nblkB * 3 * 4);
    float* bsum  = (float*)alloc((size_t)nblkB * 3 * 4);
    float* gM    = (float*)alloc(16);
    float* gS    = (float*)alloc(16);
    (void)ws_size; (void)n_in; (void)out_size;

    k_binA<<<NC, 512, 0, stream>>>(esrc, edst, bdata, cbase, ccnt, E, K,
                                   embed, xq0, nrm0, N);
    k_binB<<<K, 512, 0, stream>>>(bdata, cbase, ccnt, startp, endp, colw, N, NC, K);

    const int nblkN4 = (N + (TPB / 4) - 1) / (TPB / 4);
    k_agnn<<<nblkN4, TPB, 0, stream>>>(xq0, nrm0, startp, endp, colw, beta, 0, xq1, nrm1, N, 1);
    k_agnn<<<nblkN4, TPB, 0, stream>>>(xq1, nrm1, startp, endp, colw, beta, 1, xh2, nullptr, N, 0);

    k_mlp<<<nblkB, TPB, 0, stream>>>(xh2, home, away, w0, b0, w1, b1, w2, b2,
                                     zbuf, bmax, bsum, B);
    k_lse<<<1, 256, 0, stream>>>(bmax, bsum, gM, gS, nblkB);
    const int total = B * 3;
    k_final<<<(total + TPB - 1) / TPB, TPB, 0, stream>>>(zbuf, gM, gS, (float*)d_out, total);
}

// Round 10
// 245.731 us; speedup vs baseline: 1.0795x; 1.0136x over previous
//
#include <hip/hip_runtime.h>
#include <hip/hip_fp16.h>
#include <math.h>

#define TPB 256
#define NPB 512          // nodes per bucket (power of 2)
#define NPB_SHIFT 9
#define EPB 8192         // edges per phase-A chunk (= one block's private segment)
#define EPW 16           // EPB / 512 threads
#define BCAP 12288       // per-bucket col-window capacity (mean ~8192, +45 sigma)
#define RSTRIDE 32       // packed node record: 16B fp8 row + 4B norm + 12B pad

typedef float v2f __attribute__((ext_vector_type(2)));

__device__ __forceinline__ float leaky_relu(float v) { return v > 0.0f ? v : 0.01f * v; }

__device__ __forceinline__ float dot4(float4 a, float4 b) {
    return a.x * b.x + a.y * b.y + a.z * b.z + a.w * b.w;
}
__device__ __forceinline__ float4 f4_scale(float4 a, float s) {
    return make_float4(a.x * s, a.y * s, a.z * s, a.w * s);
}
// a += w*y
__device__ __forceinline__ float4 f4_acc(float4 a, float w, float4 y) {
    return make_float4(fmaf(w, y.x, a.x), fmaf(w, y.y, a.y),
                       fmaf(w, y.z, a.z), fmaf(w, y.w, a.w));
}
__device__ __forceinline__ float4 f4_add_shfl(float4 v, int d) {
    return make_float4(v.x + __shfl_xor(v.x, d, 64), v.y + __shfl_xor(v.y, d, 64),
                       v.z + __shfl_xor(v.z, d, 64), v.w + __shfl_xor(v.w, d, 64));
}
__device__ __forceinline__ float4 leaky4(float4 v) {
    return make_float4(leaky_relu(v.x), leaky_relu(v.y), leaky_relu(v.z), leaky_relu(v.w));
}

// HW fp8 e4m3 (OCP) pack/unpack: 4 elements <-> one dword
__device__ __forceinline__ float4 dec4(unsigned w) {
    v2f lo = __builtin_amdgcn_cvt_pk_f32_fp8((int)w, false);
    v2f hi = __builtin_amdgcn_cvt_pk_f32_fp8((int)w, true);
    return make_float4(lo.x, lo.y, hi.x, hi.y);
}
__device__ __forceinline__ unsigned enc4(float4 v) {
    int r = __builtin_amdgcn_cvt_pk_fp8_f32(v.x, v.y, 0, false);
    r = __builtin_amdgcn_cvt_pk_fp8_f32(v.z, v.w, r, true);
    return (unsigned)r;
}

// fp16 quarter helpers (MLP input rows)
__device__ __forceinline__ float4 load_h4(const __half* row, int l) {
    union { float2 f; __half h[4]; } u;
    u.f = ((const float2*)row)[l];
    return make_float4(__half2float(u.h[0]), __half2float(u.h[1]),
                       __half2float(u.h[2]), __half2float(u.h[3]));
}
__device__ __forceinline__ void store_h4(__half* row, int l, float4 v) {
    union { float2 f; __half h[4]; } u;
    u.h[0] = __float2half(v.x); u.h[1] = __float2half(v.y);
    u.h[2] = __float2half(v.z); u.h[3] = __float2half(v.w);
    ((float2*)row)[l] = u.f;
}

// packed-record accessors (base is char*, record i at i*RSTRIDE)
__device__ __forceinline__ uint4 rec_q(const char* base, int i) {
    return *(const uint4*)(base + (size_t)i * RSTRIDE);
}
__device__ __forceinline__ float rec_n(const char* base, int i) {
    return *(const float*)(base + (size_t)i * RSTRIDE + 16);
}

// ---------------- build phase A (+ fused prep) ----------------
// Per-chunk LDS counting sort -> private contiguous bdata segment (coalesced,
// zero global atomics). Tail: fp32 embed row -> packed record {fp8 row, norm}.
__global__ void k_binA(const int* __restrict__ src, const int* __restrict__ dst,
                       unsigned* __restrict__ bdata, int* __restrict__ cbase,
                       int* __restrict__ ccnt, int E, int K,
                       const float* __restrict__ x, char* __restrict__ xqn,
                       int N) {
    __shared__ int hist[512];
    __shared__ int scan_[512];
    __shared__ unsigned lcol[EPB];   // 32 KB
    int t = threadIdx.x;
    int c = blockIdx.x;
    int e0 = c * EPB;
    int e1 = min(e0 + EPB, E);
    hist[t] = 0;
    __syncthreads();
    int myd[EPW], mys[EPW];
#pragma unroll
    for (int k = 0; k < EPW; ++k) {
        int e = e0 + t + k * 512;
        int d = (e < e1) ? dst[e] : -1;
        mys[k] = (e < e1) ? src[e] : 0;
        myd[k] = d;
        if (d >= 0) atomicAdd(&hist[d >> NPB_SHIFT], 1);
    }
    __syncthreads();
    int v = hist[t];
    scan_[t] = v;
    __syncthreads();
    for (int off = 1; off < 512; off <<= 1) {
        int a = (t >= off) ? scan_[t - off] : 0;
        __syncthreads();
        scan_[t] += a;
        __syncthreads();
    }
    int excl = scan_[t] - v;
    if (t < K) {
        cbase[(size_t)c * K + t] = excl;
        ccnt[(size_t)c * K + t] = v;
    }
    __syncthreads();
    hist[t] = excl;   // reuse as cursor
    __syncthreads();
#pragma unroll
    for (int k = 0; k < EPW; ++k) {
        int d = myd[k];
        if (d >= 0) {
            int p = atomicAdd(&hist[d >> NPB_SHIFT], 1);
            lcol[p] = ((unsigned)(d & (NPB - 1)) << 18) | (unsigned)mys[k];
        }
    }
    __syncthreads();
    unsigned* outp = bdata + (size_t)c * EPB;
    int tot = e1 - e0;
    for (int i = t; i < tot; i += 512) outp[i] = lcol[i];
    // ---- fused prep: packed record ----
    int i = c * 512 + t;
    if (i < N) {
        const float4* xp = (const float4*)(x + (size_t)i * 16);
        float4 a = xp[0], b = xp[1], cc = xp[2], d = xp[3];
        float ss = dot4(a, a) + dot4(b, b) + dot4(cc, cc) + dot4(d, d);
        float nn = fmaxf(sqrtf(ss), 1e-12f);
        float inv = 1.0f / nn;
        char* rp = xqn + (size_t)i * RSTRIDE;
        *(uint4*)rp = make_uint4(enc4(f4_scale(a, inv)), enc4(f4_scale(b, inv)),
                                 enc4(f4_scale(cc, inv)), enc4(f4_scale(d, inv)));
        *(float*)(rp + 16) = nn;
    }
}

// ---------------- build phase B: per-bucket CSR, thread-per-run ----------------
__global__ void k_binB(const unsigned* __restrict__ bdata, const int* __restrict__ cbase,
                       const int* __restrict__ ccnt,
                       int* __restrict__ startp, int* __restrict__ endp,
                       int* __restrict__ col, int N, int NC, int K) {
    __shared__ int cb[512];
    __shared__ int cc[512];
    __shared__ int ldeg[NPB];
    __shared__ int lscan[NPB];
    int b = blockIdx.x, t = threadIdx.x;
    int n0 = b << NPB_SHIFT;
    int nn = min(NPB, N - n0);
    cb[t] = (t < NC) ? cbase[(size_t)t * K + b] : 0;
    cc[t] = (t < NC) ? ccnt[(size_t)t * K + b] : 0;
    ldeg[t] = 0;
    __syncthreads();
    int mycnt = (t < NC) ? cc[t] : 0;
    const unsigned* myp = bdata + (size_t)t * EPB + cb[t];
    for (int k = 0; k < mycnt; ++k) {
        unsigned e = myp[k];
        atomicAdd(&ldeg[e >> 18], 1);
    }
    __syncthreads();
    int dv = ldeg[t];
    lscan[t] = dv;
    __syncthreads();
    for (int off = 1; off < NPB; off <<= 1) {
        int a = (t >= off) ? lscan[t - off] : 0;
        __syncthreads();
        lscan[t] += a;
        __syncthreads();
    }
    int excl = lscan[t] - dv;
    int gb = b * BCAP;
    if (t < nn) {
        startp[n0 + t] = gb + excl;
        endp[n0 + t] = gb + excl + dv;
    }
    __syncthreads();
    ldeg[t] = excl;   // cursor
    __syncthreads();
    for (int k = 0; k < mycnt; ++k) {
        unsigned e = myp[k];
        int pos = atomicAdd(&ldeg[e >> 18], 1);
        col[gb + pos] = (int)(e & 0x3FFFFu);
    }
}

// ---------------- AGNN conv: 4 lanes per node, full row per lane ----------------
// Packed 32B records: the norm load always hits the row's cache line -> ONE
// random line touch per edge (was two: xq + separate nrm table). No-max
// softmax (|alpha|<=beta -> exp safe). Depth-2 prefetch.
__global__ void k_agnn(const char* __restrict__ xqn,
                       const int* __restrict__ startp, const int* __restrict__ endp,
                       const int* __restrict__ col,
                       const float* __restrict__ beta_ptr, int beta_idx,
                       void* __restrict__ out, int n, int fp8_out) {
    int t = threadIdx.x;
    int l = t & 3;
    int i = blockIdx.x * (TPB / 4) + (t >> 2);
    if (i >= n) return;
    float bet = beta_ptr[beta_idx];
    uint4 rowi = rec_q(xqn, i);
    float ni = rec_n(xqn, i);
    float4 x0 = dec4(rowi.x), x1 = dec4(rowi.y), x2 = dec4(rowi.z), x3 = dec4(rowi.w);
    float4 q0 = f4_scale(x0, bet), q1 = f4_scale(x1, bet),
           q2 = f4_scale(x2, bet), q3 = f4_scale(x3, bet);
    float s;
    float4 a0, a1, a2, a3;
    if (l == 0) {
        float aself = dot4(x0, q0) + dot4(x1, q1) + dot4(x2, q2) + dot4(x3, q3);
        float w = __expf(aself);
        s = w;
        float wi = w * ni;
        a0 = f4_scale(x0, wi); a1 = f4_scale(x1, wi);
        a2 = f4_scale(x2, wi); a3 = f4_scale(x3, wi);
    } else {
        s = 0.0f;
        a0 = a1 = a2 = a3 = make_float4(0.f, 0.f, 0.f, 0.f);
    }
    int e1 = endp[i];
    int e = startp[i] + l;
    uint4 rA = make_uint4(0, 0, 0, 0), rB = make_uint4(0, 0, 0, 0);
    float nA = 0.0f, nB = 0.0f;
    if (e < e1) { int j = col[e]; rA = rec_q(xqn, j); nA = rec_n(xqn, j); }
    if (e + 4 < e1) { int j = col[e + 4]; rB = rec_q(xqn, j); nB = rec_n(xqn, j); }
    for (; e < e1; e += 4) {
        uint4 rC = make_uint4(0, 0, 0, 0);
        float nC = 0.0f;
        if (e + 8 < e1) { int j = col[e + 8]; rC = rec_q(xqn, j); nC = rec_n(xqn, j); }
        float4 y0 = dec4(rA.x), y1 = dec4(rA.y), y2 = dec4(rA.z), y3 = dec4(rA.w);
        float d = dot4(y0, q0) + dot4(y1, q1) + dot4(y2, q2) + dot4(y3, q3);
        float w = __expf(d);
        s += w;
        float wn = w * nA;
        a0 = f4_acc(a0, wn, y0);
        a1 = f4_acc(a1, wn, y1);
        a2 = f4_acc(a2, wn, y2);
        a3 = f4_acc(a3, wn, y3);
        rA = rB; nA = nB; rB = rC; nB = nC;
    }
    // merge 4 lane-states: plain sums (butterfly)
#pragma unroll
    for (int d_ = 1; d_ < 4; d_ <<= 1) {
        s += __shfl_xor(s, d_, 64);
        a0 = f4_add_shfl(a0, d_);
        a1 = f4_add_shfl(a1, d_);
        a2 = f4_add_shfl(a2, d_);
        a3 = f4_add_shfl(a3, d_);
    }
    float inv = 1.0f / (s + 1e-16f);
    float4 o0 = leaky4(f4_scale(a0, inv));
    float4 o1 = leaky4(f4_scale(a1, inv));
    float4 o2 = leaky4(f4_scale(a2, inv));
    float4 o3 = leaky4(f4_scale(a3, inv));
    float4 oq = (l == 0) ? o0 : (l == 1) ? o1 : (l == 2) ? o2 : o3;
    if (fp8_out) {
        float ss = dot4(o0, o0) + dot4(o1, o1) + dot4(o2, o2) + dot4(o3, o3);
        float nn = fmaxf(sqrtf(ss), 1e-12f);
        char* rp = (char*)out + (size_t)i * RSTRIDE;
        ((unsigned*)rp)[l] = enc4(f4_scale(oq, 1.0f / nn));
        if (l == 0) *(float*)(rp + 16) = nn;
    } else {
        store_h4((__half*)out + (size_t)i * 16, l, oq);
    }
}

// ---------------- MLP head + fused per-block logsumexp partials ----------------
__global__ void k_mlp(const __half* __restrict__ x, const int* __restrict__ home,
                      const int* __restrict__ away,
                      const float* __restrict__ w0, const float* __restrict__ b0,
                      const float* __restrict__ w1, const float* __restrict__ b1,
                      const float* __restrict__ w2, const float* __restrict__ b2,
                      float* __restrict__ z, float* __restrict__ bmax,
                      float* __restrict__ bsum, int nb) {
    __shared__ float sw0[192], sw1[96], sw2[48], sb0[6], sb1[16], sb2[3];
    __shared__ float rmax[4][3];
    __shared__ float rsum[4][3];
    int t = threadIdx.x;
    if (t < 192) sw0[t] = w0[t];
    if (t < 96)  sw1[t] = w1[t];
    if (t < 48)  sw2[t] = w2[t];
    if (t < 6)   sb0[t] = b0[t];
    if (t < 16)  sb1[t] = b1[t];
    if (t < 3)   sb2[t] = b2[t];
    __syncthreads();
    int i = blockIdx.x * blockDim.x + t;
    bool act = i < nb;
    float z0 = -3.4e38f, z1 = -3.4e38f, z2 = -3.4e38f;
    if (act) {
        float h[32];
        const __half* hr = x + (size_t)home[i] * 16;
        const __half* ar = x + (size_t)away[i] * 16;
#pragma unroll
        for (int k = 0; k < 4; ++k) {
            float4 v = load_h4(hr, k);
            h[4 * k + 0] = v.x; h[4 * k + 1] = v.y; h[4 * k + 2] = v.z; h[4 * k + 3] = v.w;
            float4 u = load_h4(ar, k);
            h[16 + 4 * k + 0] = u.x; h[16 + 4 * k + 1] = u.y;
            h[16 + 4 * k + 2] = u.z; h[16 + 4 * k + 3] = u.w;
        }
        float t0[6];
#pragma unroll
        for (int o = 0; o < 6; ++o) {
            float acc = sb0[o];
#pragma unroll
            for (int k = 0; k < 32; ++k) acc = fmaf(h[k], sw0[k * 6 + o], acc);
            t0[o] = leaky_relu(acc);
        }
        float t1[16];
#pragma unroll
        for (int o = 0; o < 16; ++o) {
            float acc = sb1[o];
#pragma unroll
            for (int k = 0; k < 6; ++k) acc = fmaf(t0[k], sw1[k * 16 + o], acc);
            t1[o] = leaky_relu(acc);
        }
        float zz[3];
#pragma unroll
        for (int o = 0; o < 3; ++o) {
            float acc = sb2[o];
#pragma unroll
            for (int k = 0; k < 16; ++k) acc = fmaf(t1[k], sw2[k * 3 + o], acc);
            zz[o] = leaky_relu(acc);
            z[(size_t)i * 3 + o] = zz[o];
        }
        z0 = zz[0]; z1 = zz[1]; z2 = zz[2];
    }
    float w0_ = z0, w1_ = z1, w2_ = z2;
#pragma unroll
    for (int off = 32; off > 0; off >>= 1) {
        w0_ = fmaxf(w0_, __shfl_down(w0_, off));
        w1_ = fmaxf(w1_, __shfl_down(w1_, off));
        w2_ = fmaxf(w2_, __shfl_down(w2_, off));
    }
    int wid = t >> 6;
    if ((t & 63) == 0) { rmax[wid][0] = w0_; rmax[wid][1] = w1_; rmax[wid][2] = w2_; }
    __syncthreads();
    float M0 = fmaxf(fmaxf(rmax[0][0], rmax[1][0]), fmaxf(rmax[2][0], rmax[3][0]));
    float M1 = fmaxf(fmaxf(rmax[0][1], rmax[1][1]), fmaxf(rmax[2][1], rmax[3][1]));
    float M2 = fmaxf(fmaxf(rmax[0][2], rmax[1][2]), fmaxf(rmax[2][2], rmax[3][2]));
    float e0 = act ? __expf(z0 - M0) : 0.0f;
    float e1 = act ? __expf(z1 - M1) : 0.0f;
    float e2 = act ? __expf(z2 - M2) : 0.0f;
#pragma unroll
    for (int off = 32; off > 0; off >>= 1) {
        e0 += __shfl_down(e0, off);
        e1 += __shfl_down(e1, off);
        e2 += __shfl_down(e2, off);
    }
    if ((t & 63) == 0) { rsum[wid][0] = e0; rsum[wid][1] = e1; rsum[wid][2] = e2; }
    __syncthreads();
    if (t == 0) {
        float S0 = rsum[0][0] + rsum[1][0] + rsum[2][0] + rsum[3][0];
        float S1 = rsum[0][1] + rsum[1][1] + rsum[2][1] + rsum[3][1];
        float S2 = rsum[0][2] + rsum[1][2] + rsum[2][2] + rsum[3][2];
        bmax[blockIdx.x * 3 + 0] = M0; bmax[blockIdx.x * 3 + 1] = M1; bmax[blockIdx.x * 3 + 2] = M2;
        bsum[blockIdx.x * 3 + 0] = S0; bsum[blockIdx.x * 3 + 1] = S1; bsum[blockIdx.x * 3 + 2] = S2;
    }
}

// merge per-block (max, sumexp) partials -> global per-column
__global__ void k_lse(const float* __restrict__ bmax, const float* __restrict__ bsum,
                      float* __restrict__ gM, float* __restrict__ gS, int nblk) {
    __shared__ float lm[4][3];
    __shared__ float ls[4][3];
    int t = threadIdx.x;
    float M0 = -3.4e38f, M1 = -3.4e38f, M2 = -3.4e38f;
    float S0 = 0.f, S1 = 0.f, S2 = 0.f;
    for (int b = t; b < nblk; b += 256) {
        float m0 = bmax[b * 3 + 0], s0 = bsum[b * 3 + 0];
        float n0 = fmaxf(M0, m0); S0 = S0 * __expf(M0 - n0) + s0 * __expf(m0 - n0); M0 = n0;
        float m1 = bmax[b * 3 + 1], s1 = bsum[b * 3 + 1];
        float n1 = fmaxf(M1, m1); S1 = S1 * __expf(M1 - n1) + s1 * __expf(m1 - n1); M1 = n1;
        float m2 = bmax[b * 3 + 2], s2 = bsum[b * 3 + 2];
        float n2 = fmaxf(M2, m2); S2 = S2 * __expf(M2 - n2) + s2 * __expf(m2 - n2); M2 = n2;
    }
#pragma unroll
    for (int off = 32; off > 0; off >>= 1) {
        float mo, so, nm;
        mo = __shfl_down(M0, off); so = __shfl_down(S0, off);
        nm = fmaxf(M0, mo); S0 = S0 * __expf(M0 - nm) + so * __expf(mo - nm); M0 = nm;
        mo = __shfl_down(M1, off); so = __shfl_down(S1, off);
        nm = fmaxf(M1, mo); S1 = S1 * __expf(M1 - nm) + so * __expf(mo - nm); M1 = nm;
        mo = __shfl_down(M2, off); so = __shfl_down(S2, off);
        nm = fmaxf(M2, mo); S2 = S2 * __expf(M2 - nm) + so * __expf(mo - nm); M2 = nm;
    }
    int wid = t >> 6;
    if ((t & 63) == 0) {
        lm[wid][0] = M0; lm[wid][1] = M1; lm[wid][2] = M2;
        ls[wid][0] = S0; ls[wid][1] = S1; ls[wid][2] = S2;
    }
    __syncthreads();
    if (t == 0) {
        for (int w = 1; w < 4; ++w) {
            float nm;
            nm = fmaxf(M0, lm[w][0]); S0 = S0 * __expf(M0 - nm) + ls[w][0] * __expf(lm[w][0] - nm); M0 = nm;
            nm = fmaxf(M1, lm[w][1]); S1 = S1 * __expf(M1 - nm) + ls[w][1] * __expf(lm[w][1] - nm); M1 = nm;
            nm = fmaxf(M2, lm[w][2]); S2 = S2 * __expf(M2 - nm) + ls[w][2] * __expf(lm[w][2] - nm); M2 = nm;
        }
        gM[0] = M0; gM[1] = M1; gM[2] = M2;
        gS[0] = S0; gS[1] = S1; gS[2] = S2;
    }
}

__global__ void k_final(const float* __restrict__ z, const float* __restrict__ gM,
                        const float* __restrict__ gS, float* __restrict__ out, int total) {
    int i = blockIdx.x * blockDim.x + threadIdx.x;
    if (i >= total) return;
    int c = i % 3;
    out[i] = z[i] - gM[c] - logf(gS[c]);
}

extern "C" void kernel_launch(void* const* d_in, const int* in_sizes, int n_in,
                              void* d_out, int out_size, void* d_ws, size_t ws_size,
                              hipStream_t stream) {
    const float* embed = (const float*)d_in[0];
    const float* beta  = (const float*)d_in[1];
    const float* w0 = (const float*)d_in[2];
    const float* b0 = (const float*)d_in[3];
    const float* w1 = (const float*)d_in[4];
    const float* b1 = (const float*)d_in[5];
    const float* w2 = (const float*)d_in[6];
    const float* b2 = (const float*)d_in[7];
    const int* eidx = (const int*)d_in[8];
    const int* home = (const int*)d_in[9];
    const int* away = (const int*)d_in[10];

    const int N = in_sizes[0] / 16;
    const int E = in_sizes[8] / 2;
    const int B = in_sizes[9];
    const int* esrc = eidx;
    const int* edst = eidx + E;
    const int K = (N + NPB - 1) >> NPB_SHIFT;       // 391 buckets
    const int NC = (E + EPB - 1) / EPB;             // 391 chunks (<=512)

    char* ws = (char*)d_ws;
    size_t off = 0;
    auto alloc = [&](size_t bytes) -> char* {
        off = (off + 255) & ~(size_t)255;
        char* p = ws + off;
        off += bytes;
        return p;
    };
    // union region: bdata (build) aliases {xqn1, zbuf} (both written after binB)
    size_t bdata_bytes = (size_t)NC * EPB * 4;   // 12.8 MB
    size_t alias_bytes = (((size_t)N * RSTRIDE + 511) & ~(size_t)255) + (size_t)B * 3 * 4;
    char* U = alloc(bdata_bytes > alias_bytes ? bdata_bytes : alias_bytes);
    unsigned* bdata = (unsigned*)U;
    char* xqn1  = U;                                                        // N*32B packed
    float* zbuf = (float*)(U + (((size_t)N * RSTRIDE + 511) & ~(size_t)255)); // B*3*4B

    int* startp  = (int*)alloc((size_t)N * 4);
    int* endp    = (int*)alloc((size_t)N * 4);
    int* colw    = (int*)alloc((size_t)K * BCAP * 4);   // padded per-bucket windows
    int* cbase   = (int*)alloc((size_t)NC * K * 4);
    int* ccnt    = (int*)alloc((size_t)NC * K * 4);
    char* xqn0   = alloc((size_t)N * RSTRIDE);
    __half* xh2  = (__half*)alloc((size_t)N * 32);
    const int nblkB = (B + TPB - 1) / TPB;
    float* bmax  = (float*)alloc((size_t)nblkB * 3 * 4);
    float* bsum  = (float*)alloc((size_t)nblkB * 3 * 4);
    float* gM    = (float*)alloc(16);
    float* gS    = (float*)alloc(16);
    (void)ws_size; (void)n_in; (void)out_size;

    k_binA<<<NC, 512, 0, stream>>>(esrc, edst, bdata, cbase, ccnt, E, K,
                                   embed, xqn0, N);
    k_binB<<<K, 512, 0, stream>>>(bdata, cbase, ccnt, startp, endp, colw, N, NC, K);

    const int nblkN4 = (N + (TPB / 4) - 1) / (TPB / 4);
    k_agnn<<<nblkN4, TPB, 0, stream>>>(xqn0, startp, endp, colw, beta, 0, xqn1, N, 1);
    k_agnn<<<nblkN4, TPB, 0, stream>>>(xqn1, startp, endp, colw, beta, 1, xh2, N, 0);

    k_mlp<<<nblkB, TPB, 0, stream>>>(xh2, home, away, w0, b0, w1, b1, w2, b2,
                                     zbuf, bmax, bsum, B);
    k_lse<<<1, 256, 0, stream>>>(bmax, bsum, gM, gS, nblkB);
    const int total = B * 3;
    k_final<<<(total + TPB - 1) / TPB, TPB, 0, stream>>>(zbuf, gM, gS, (float*)d_out, total);
}